// Round 10
// baseline (608.118 us; speedup 1.0000x reference)
//
#include <hip/hip_runtime.h>
#include <hip/hip_bf16.h>
#include <math.h>

// ---------------------------------------------------------------------------
// BinaryCNN round 10: B-operands direct from global (L2-hot weights),
// zero K-loop barriers in conv2/conv3/conv4/fc. Accumulation order unchanged.
// ---------------------------------------------------------------------------

#define EPS 1e-5f

typedef __attribute__((ext_vector_type(8))) short bf16x8;
typedef __attribute__((ext_vector_type(4))) float f32x4;
typedef __attribute__((ext_vector_type(16))) float f32x16;
typedef __attribute__((ext_vector_type(4))) int i32x4;

__device__ __forceinline__ short f2bf(float f) {
  unsigned u = __builtin_bit_cast(unsigned, f);
  unsigned r = u + 0x7FFFu + ((u >> 16) & 1u);   // RNE
  return (short)(r >> 16);
}
__device__ __forceinline__ float bf2f(short h) {
  unsigned u = ((unsigned)(unsigned short)h) << 16;
  return __builtin_bit_cast(float, u);
}
__device__ __forceinline__ int swz2(int pin) {         // conv2: RS=32, S=4
  return (pin ^ (pin >> 2) ^ (pin >> 5)) & 3;
}
__device__ __forceinline__ int swz3(int pin) {         // conv3: RS=16, S=8
  return (pin ^ (pin >> 2) ^ (pin >> 4)) & 7;
}
__device__ __forceinline__ float qclip(float w, float s) {
  return fminf(fmaxf(rintf(w / s), -128.f), 127.f);
}

// ---------------- fused prep: scales + all weight repacks -------------------
struct PrepArgs {
  const float* w[8];
  short* dsth[8];
  float* dstf;
  float* sc;
  int sco[8];
  int cik[8];
  int kind[8];
  int KK[8];
  int CI[8];
  int OCCH[8];
  int KC[8];
  int cum[9];
};

__global__ __launch_bounds__(256) void prep_all(PrepArgs a) {
  int b = blockIdx.x;
  int t = 0;
  while (b >= a.cum[t + 1]) t++;
  int oc = b - a.cum[t];
  int cik = a.cik[t];
  const float* src = a.w[t] + (size_t)oc * cik;
  float m = 0.f;
  for (int i = threadIdx.x; i < cik; i += 256) m = fmaxf(m, fabsf(src[i]));
  #pragma unroll
  for (int o = 1; o < 64; o <<= 1) m = fmaxf(m, __shfl_xor(m, o));
  __shared__ float red[4];
  __shared__ float ssh;
  if ((threadIdx.x & 63) == 0) red[threadIdx.x >> 6] = m;
  __syncthreads();
  if (threadIdx.x == 0) {
    m = fmaxf(fmaxf(red[0], red[1]), fmaxf(red[2], red[3]));
    float s = fmaxf(m / 127.0f, 1e-8f);
    ssh = s;
    a.sc[a.sco[t] + oc] = s;
  }
  __syncthreads();
  const float s = ssh;
  const int kind = a.kind[t];
  short* dst = a.dsth[t];
  if (kind == 0) {
    for (int tt = threadIdx.x; tt < 32; tt += 256) {
      float q = (tt < 25) ? qclip(src[tt], s) : 0.f;
      dst[(((oc >> 4) * 4 + (tt >> 3)) * 16 + (oc & 15)) * 8 + (tt & 7)] = f2bf(q);
    }
  } else if (kind == 1) {
    const int KK = a.KK[t], CI = a.CI[t], OCCH = a.OCCH[t];
    const int NT32 = OCCH >> 5, KS16 = CI >> 4;
    const int chunk = oc / OCCH, ocl = oc - chunk * OCCH;
    const int nt = ocl >> 5, n32 = ocl & 31;
    for (int idx = threadIdx.x; idx < cik; idx += 256) {
      int ci = idx / KK, kk = idx - ci * KK;
      float q = qclip(src[idx], s);
      int ks = ci >> 4, hh = (ci >> 3) & 1, j = ci & 7;
      size_t d = ((((size_t)(chunk * KK + kk) * NT32 + nt) * KS16 + ks) * 64 +
                  hh * 32 + n32) * 8 + j;
      dst[d] = f2bf(q);
    }
  } else if (kind == 2) {
    const int KK = a.KK[t], CI = a.CI[t], OCCH = a.OCCH[t];
    const int NTC = OCCH >> 4, KS = CI >> 5;
    const int chunk = oc / OCCH, ocl = oc - chunk * OCCH;
    const int ntl = ocl >> 4, mr = ocl & 15;
    for (int idx = threadIdx.x; idx < cik; idx += 256) {
      int ci = idx / KK, kk = idx - ci * KK;
      float q = qclip(src[idx], s);
      int ks = ci >> 5, qq = (ci >> 3) & 3, j = ci & 7;
      size_t d = ((((((size_t)(chunk * KK + kk) * NTC + ntl) * KS + ks) * 4 + qq) *
                   16 + mr)) * 8 + j;
      dst[d] = f2bf(q);
    }
  } else if (kind == 3) {
    const int KC = a.KC[t];
    const int nblk = oc >> 6, ntl = (oc >> 4) & 3, mr = oc & 15;
    for (int k = threadIdx.x; k < cik; k += 256) {
      float q = qclip(src[k], s);
      size_t d = ((((((size_t)nblk * KC + (k >> 7)) * 4 + ntl) * 4 + ((k >> 5) & 3)) *
                   4 + ((k >> 3) & 3)) * 16 + mr) * 8 + (k & 7);
      dst[d] = f2bf(q);
    }
  } else {
    for (int k = threadIdx.x; k < cik; k += 256)
      a.dstf[(size_t)oc * cik + k] = qclip(src[k], s) * s;
  }
}

// ------ fold BN (+conv bias, + int-weight scale) into per-channel A,B ------
struct BnArgs {
  const float* p[7][5];   // b, g, be, mu, va
  const float* wsc;
  float* ab;
  int C[7];
  int abo[7];
  int sco[7];
  int cum[8];
};

__global__ __launch_bounds__(256) void bn_all(BnArgs a) {
  int i = blockIdx.x * 256 + threadIdx.x;
  if (i >= a.cum[7]) return;
  int t = 0;
  while (i >= a.cum[t + 1]) t++;
  int c = i - a.cum[t];
  float A = a.p[t][1][c] / sqrtf(a.p[t][4][c] + EPS);
  float B = (a.p[t][0][c] - a.p[t][3][c]) * A + a.p[t][2][c];
  a.ab[a.abo[t] + c] = A * a.wsc[a.sco[t] + c];
  a.ab[a.abo[t] + a.C[t] + c] = B;
}

// ---------------- conv1: padded source, per-pixel im2col, MFMA -------------
__global__ __launch_bounds__(448, 2) void conv1_mfma(
    const float* __restrict__ x, const short* __restrict__ wb1,
    const float* __restrict__ ab, short* __restrict__ out) {
  __shared__ __align__(16) float spad[1024];     // 32x32 zero-padded fp32
  __shared__ __align__(16) short sim[784 * 32];
  __shared__ __align__(16) short sw1[1024];
  const int tid = threadIdx.x;
  const int img = blockIdx.x;
  for (int i = tid; i < 1024; i += 448) spad[i] = 0.f;
  for (int i = tid; i < 1024; i += 448) sw1[i] = wb1[i];
  __syncthreads();
  for (int i = tid; i < 784; i += 448)
    spad[(i / 28 + 2) * 32 + (i % 28) + 2] = x[(size_t)img * 784 + i];
  __syncthreads();
  for (int p = tid; p < 784; p += 448) {
    const int py = p / 28, px = p - py * 28;
    const float* sp = &spad[py * 32 + px];
    short v[32];
    #pragma unroll
    for (int ty = 0; ty < 5; ++ty)
      #pragma unroll
      for (int tx = 0; tx < 5; ++tx)
        v[ty * 5 + tx] = f2bf(sp[ty * 32 + tx]);
    #pragma unroll
    for (int j = 25; j < 32; ++j) v[j] = 0;
    #pragma unroll
    for (int j = 0; j < 4; ++j)
      *(bf16x8*)&sim[p * 32 + j * 8] = *(const bf16x8*)&v[j * 8];
  }
  __syncthreads();
  const int lane = tid & 63, wv = tid >> 6;
  const int mrow = lane & 15, quad = lane >> 4;
  f32x4 acc[7][2];
  #pragma unroll
  for (int i = 0; i < 7; ++i) {
    acc[i][0] = (f32x4){0.f, 0.f, 0.f, 0.f};
    acc[i][1] = (f32x4){0.f, 0.f, 0.f, 0.f};
  }
  #pragma unroll
  for (int i = 0; i < 7; ++i) {
    const int mt = wv * 7 + i;
    const bf16x8 a = *(const bf16x8*)&sim[(mt * 16 + mrow) * 32 + quad * 8];
    #pragma unroll
    for (int nt = 0; nt < 2; ++nt) {
      const bf16x8 b = *(const bf16x8*)&sw1[(nt * 4 + quad) * 128 + mrow * 8];
      acc[i][nt] = __builtin_amdgcn_mfma_f32_16x16x32_bf16(a, b, acc[i][nt], 0, 0, 0);
    }
  }
  #pragma unroll
  for (int i = 0; i < 7; ++i) {
    const int mt = wv * 7 + i;
    #pragma unroll
    for (int nt = 0; nt < 2; ++nt) {
      const int oc = nt * 16 + mrow;
      const float A = ab[oc], Bc = ab[32 + oc];
      #pragma unroll
      for (int r = 0; r < 4; ++r) {
        const int p = mt * 16 + quad * 4 + r;
        float v = fminf(fmaxf(acc[i][nt][r] * A + Bc, -1.f), 1.f);
        out[((size_t)img * 784 + p) * 32 + oc] = f2bf(v);
      }
    }
  }
}

// -------- conv2: half-image, zero-halo LDS image, B from global (L2) --------
// in: h1 [1024][784][32] bf16; wfrag: [25 taps][2 nt][2 ks16][64][8];
// out: h2 [1024][196][64] bf16
__global__ __launch_bounds__(256, 2) void conv2_half(
    const short* __restrict__ in, const short* __restrict__ wfrag,
    const float* __restrict__ ab, short* __restrict__ out) {
  constexpr int S = 4;                 // 16B blocks per pixel (32 ch)
  constexpr int RS = 32;               // padded row stride (cols)
  __shared__ __align__(16) short simg[18 * 32 * 32];   // 36864 B
  const int tid = threadIdx.x;
  const int img = blockIdx.x >> 1, half = blockIdx.x & 1;
  const int lane = tid & 63, wv = tid >> 6;
  const int l31 = lane & 31, h = lane >> 5;

  // zero halo: 2 pad rows (full) + 4 pad cols x 16 valid rows = 128 px
  {
    const int padrow0 = half ? 16 : 0;
    const int vrow0 = half ? 0 : 2;
    for (int c = tid; c < 512; c += 256) {
      int hp = c >> 2, blk = c & 3;
      int pin;
      if (hp < 64) {
        pin = (padrow0 + (hp >> 5)) * RS + (hp & 31);
      } else {
        int r = (hp - 64) >> 2, cc = (hp - 64) & 3;
        int col = (cc < 2) ? cc : (28 + cc);
        pin = (vrow0 + r) * RS + col;
      }
      ((i32x4*)simg)[pin * S + blk] = (i32x4){0, 0, 0, 0};
    }
  }
  // stage 16 valid rows (global rows half*12 .. +15) at local rows vrow0..
  {
    const i32x4* gin = (const i32x4*)(in + ((size_t)img * 784 + half * 12 * 28) * 32);
    const int vrow0 = half ? 0 : 2;
    for (int c = tid; c < 1792; c += 256) {
      int ps = c >> 2, blk = c & 3;
      int pin = (vrow0 + ps / 28) * RS + ps % 28 + 2;
      ((i32x4*)simg)[pin * S + (blk ^ swz2(pin))] = gin[c];
    }
  }

  int pinb[4], ppb[4];
  bool uv2[4];
  #pragma unroll
  for (int i = 0; i < 4; ++i) {
    int u = wv + i * 4;
    uv2[i] = u < 13;
    int m = u * 32 + l31;
    int ppl = m >> 2, cd = m & 3;
    bool ok = uv2[i] && (ppl < 98);
    int pr = ppl / 14, pc = ppl - pr * 14;
    int ygl = (half * 7 + pr) * 2 + (cd >> 1);
    int yll = ygl - (half * 14 - 2);
    int xc = pc * 2 + (cd & 1) + 2;
    pinb[i] = ok ? (yll * RS + xc) : (2 * RS + 2);
    ppb[i] = u * 8;
  }

  f32x16 acc[4][2];
  #pragma unroll
  for (int i = 0; i < 4; ++i)
    #pragma unroll
    for (int nt = 0; nt < 2; ++nt)
      #pragma unroll
      for (int e = 0; e < 16; ++e) acc[i][nt][e] = 0.f;

  __syncthreads();                      // the only barrier

  #pragma unroll
  for (int t = 0; t < 25; ++t) {
    const int tp = (t / 5 - 2) * RS + (t % 5 - 2);
    int pin[4], sx4[4];
    #pragma unroll
    for (int i = 0; i < 4; ++i) {
      pin[i] = pinb[i] + tp;
      sx4[i] = swz2(pin[i]);
    }
    #pragma unroll
    for (int ks = 0; ks < 2; ++ks) {
      bf16x8 af[4];
      #pragma unroll
      for (int i = 0; i < 4; ++i)
        af[i] = *(const bf16x8*)&simg[pin[i] * 32 + (((ks * 2 + h) ^ sx4[i]) * 8)];
      #pragma unroll
      for (int nt = 0; nt < 2; ++nt) {
        const bf16x8 bf = *(const bf16x8*)&wfrag[(((t * 2 + nt) * 2 + ks) * 64 + lane) * 8];
        #pragma unroll
        for (int i = 0; i < 4; ++i)
          acc[i][nt] = __builtin_amdgcn_mfma_f32_32x32x16_bf16(af[i], bf, acc[i][nt], 0, 0, 0);
      }
    }
  }

  #pragma unroll
  for (int i = 0; i < 4; ++i) {
    #pragma unroll
    for (int nt = 0; nt < 2; ++nt) {
      const int oc = nt * 32 + l31;
      const float A = ab[oc], Bc = ab[64 + oc];
      #pragma unroll
      for (int g = 0; g < 4; ++g) {
        const int ppo = ppb[i] + 2 * g + h;
        if (uv2[i] && ppo < 98) {
          float mx = fmaxf(fmaxf(acc[i][nt][g * 4 + 0], acc[i][nt][g * 4 + 1]),
                           fmaxf(acc[i][nt][g * 4 + 2], acc[i][nt][g * 4 + 3]));
          float v = fminf(fmaxf(mx * A + Bc, -1.f), 1.f);
          out[((size_t)img * 196 + half * 98 + ppo) * 64 + oc] = f2bf(v);
        }
      }
    }
  }
}

// -------- conv3: 2 imgs, zero-halo 16x16 LDS image, B from global (L2) ------
__global__ __launch_bounds__(256, 2) void conv3_pad(
    const short* __restrict__ in, const short* __restrict__ wfrag,
    const float* __restrict__ ab, short* __restrict__ out) {
  constexpr int S = 8, RS = 16;
  __shared__ __align__(16) short simg[2 * 256 * 64];    // 65536 B
  const int tid = threadIdx.x;
  const int img0 = blockIdx.x * 2;
  const int lane = tid & 63, wv = tid >> 6;
  const int l31 = lane & 31, h = lane >> 5;

  for (int c = tid; c < 960; c += 256) {
    int blk = c & 7, hp0 = c >> 3;
    int il = hp0 >= 60 ? 1 : 0, hp = hp0 - il * 60;
    int pin;
    if (hp < 32) pin = (hp >> 4) * 15 * RS + (hp & 15);
    else {
      int r = ((hp - 32) >> 1) + 1, cc = ((hp - 32) & 1) * 15;
      pin = r * RS + cc;
    }
    ((i32x4*)simg)[(il * 256 + pin) * S + blk] = (i32x4){0, 0, 0, 0};
  }
  {
    const i32x4* gin = (const i32x4*)(in + (size_t)img0 * 196 * 64);
    for (int c = tid; c < 3136; c += 256) {
      int il = c / 1568, r = c - il * 1568;
      int ps = r >> 3, blk = r & 7;
      int pin = (ps / 14 + 1) * RS + ps % 14 + 1;
      ((i32x4*)simg)[(il * 256 + pin) * S + (blk ^ swz3(pin))] = gin[c];
    }
  }

  int pinb[4], ppb[4], ilv[4];
  bool uv4[4];
  #pragma unroll
  for (int i = 0; i < 4; ++i) {
    int u = wv + i * 4;
    uv4[i] = u < 14;
    int uu = uv4[i] ? u : 0;
    int il = uu / 7, lt = uu - il * 7;
    int m = lt * 32 + l31, ppl = m >> 2, cd = m & 3;
    bool ok = uv4[i] && (ppl < 49);
    int py = ppl / 7, px = ppl - py * 7;
    int y = py * 2 + (cd >> 1), x = px * 2 + (cd & 1);
    pinb[i] = (ok ? ((y + 1) * RS + x + 1) : (RS + 1)) + il * 256;
    ilv[i] = il;
    ppb[i] = lt * 8;
  }

  f32x16 acc[4][2];
  #pragma unroll
  for (int i = 0; i < 4; ++i)
    #pragma unroll
    for (int nt = 0; nt < 2; ++nt)
      #pragma unroll
      for (int e = 0; e < 16; ++e) acc[i][nt][e] = 0.f;

  __syncthreads();                      // the only barrier

  for (int ch = 0; ch < 2; ++ch) {
    #pragma unroll
    for (int t = 0; t < 9; ++t) {
      const int tp = (t / 3 - 1) * RS + (t % 3 - 1);
      int pin[4], sx4[4];
      #pragma unroll
      for (int i = 0; i < 4; ++i) {
        pin[i] = pinb[i] + tp;
        sx4[i] = swz3(pin[i]);
      }
      #pragma unroll
      for (int ks = 0; ks < 4; ++ks) {
        bf16x8 af[4];
        #pragma unroll
        for (int i = 0; i < 4; ++i)
          af[i] = *(const bf16x8*)&simg[pin[i] * 64 + (((ks * 2 + h) ^ sx4[i]) * 8)];
        #pragma unroll
        for (int nt = 0; nt < 2; ++nt) {
          const bf16x8 bf = *(const bf16x8*)&wfrag[
              ((((ch * 9 + t) * 2 + nt) * 4 + ks) * 64 + lane) * 8];
          #pragma unroll
          for (int i = 0; i < 4; ++i)
            acc[i][nt] = __builtin_amdgcn_mfma_f32_32x32x16_bf16(af[i], bf, acc[i][nt], 0, 0, 0);
        }
      }
    }
    // epilogue for this chunk, then reset acc
    #pragma unroll
    for (int i = 0; i < 4; ++i) {
      #pragma unroll
      for (int nt = 0; nt < 2; ++nt) {
        const int oc = ch * 64 + nt * 32 + l31;
        const float A = ab[oc], Bc = ab[128 + oc];
        #pragma unroll
        for (int g = 0; g < 4; ++g) {
          const int ppo = ppb[i] + 2 * g + h;
          if (uv4[i] && ppo < 49) {
            float mx = fmaxf(fmaxf(acc[i][nt][g * 4 + 0], acc[i][nt][g * 4 + 1]),
                             fmaxf(acc[i][nt][g * 4 + 2], acc[i][nt][g * 4 + 3]));
            float v = fminf(fmaxf(mx * A + Bc, -1.f), 1.f);
            out[((size_t)(img0 + ilv[i]) * 49 + ppo) * 128 + oc] = f2bf(v);
          }
        }
        #pragma unroll
        for (int e = 0; e < 16; ++e) acc[i][nt][e] = 0.f;
      }
    }
  }
}

// -------- conv4: B from global (L2); emits h4 hi/lo in fc-frag order --------
__global__ __launch_bounds__(512, 2) void conv4_mfma(
    const short* __restrict__ in,      // h3 bf16 [img][49][128]
    const short* __restrict__ wfrag,   // [9][16][4][4][16][8]
    const float* __restrict__ ab,
    short* __restrict__ outH, short* __restrict__ outL) {
  constexpr int S = 16, NPIX = 49, PP = 9;
  __shared__ __align__(16) short simg[2 * NPIX * 128];
  const int tid = threadIdx.x;
  const int img0 = blockIdx.x * 2;
  const int lane = tid & 63, wv = tid >> 6;
  const int mrow = lane & 15, quad = lane >> 4;

  {
    const i32x4* gsrc = (const i32x4*)(in + (size_t)img0 * NPIX * 128);
    for (int c = tid; c < 2 * NPIX * S; c += 512) {
      int il = c / (NPIX * S);
      int r = c - il * (NPIX * S);
      int pix = r >> 4, blk = r & 15;
      ((i32x4*)simg)[il * NPIX * S + pix * S + (blk ^ (pix & 15))] = gsrc[c];
    }
  }

  int yy[6], xx[6], ibs[6], ppo_[6], ilv[6];
  bool rv[6], pv[6];
  #pragma unroll
  for (int i = 0; i < 6; ++i) {
    int il = i / 3, lt = i - il * 3;
    int m = lt * 16 + mrow;
    int pp = m >> 2, cd = m & 3;
    rv[i] = pp < PP;
    int py = pp / 3, px = pp - py * 3;
    yy[i] = py * 2 + (cd >> 1);
    xx[i] = px * 2 + (cd & 1);
    ibs[i] = il * NPIX * S;
    ilv[i] = il;
    ppo_[i] = lt * 4 + quad;
    pv[i] = ppo_[i] < PP;
  }
  const int nt0 = wv, nt1 = wv + 8;
  f32x4 acc[6][2];
  #pragma unroll
  for (int i = 0; i < 6; ++i) {
    acc[i][0] = (f32x4){0.f, 0.f, 0.f, 0.f};
    acc[i][1] = (f32x4){0.f, 0.f, 0.f, 0.f};
  }
  __syncthreads();                      // the only barrier

  #pragma unroll
  for (int t = 0; t < 9; ++t) {
    const int dy = t / 3 - 1, dx = t % 3 - 1;
    #pragma unroll
    for (int ks = 0; ks < 4; ++ks) {
      bf16x8 af[6];
      #pragma unroll
      for (int i = 0; i < 6; ++i) {
        int iy = yy[i] + dy, ix = xx[i] + dx;
        bool ok = rv[i] && (unsigned)iy < 7u && (unsigned)ix < 7u;
        int pin = iy * 7 + ix;
        int blk = (ks * 4 + quad) ^ (pin & 15);
        af[i] = ok ? *(const bf16x8*)&simg[(ibs[i] + pin * S + blk) * 8]
                   : (bf16x8){0, 0, 0, 0, 0, 0, 0, 0};
      }
      const bf16x8 b0 = *(const bf16x8*)&wfrag[
          (size_t)t * 32768 + ((nt0 * 4 + ks) * 4 + quad) * 128 + mrow * 8];
      const bf16x8 b1 = *(const bf16x8*)&wfrag[
          (size_t)t * 32768 + ((nt1 * 4 + ks) * 4 + quad) * 128 + mrow * 8];
      #pragma unroll
      for (int i = 0; i < 6; ++i) {
        acc[i][0] = __builtin_amdgcn_mfma_f32_16x16x32_bf16(af[i], b0, acc[i][0], 0, 0, 0);
        acc[i][1] = __builtin_amdgcn_mfma_f32_16x16x32_bf16(af[i], b1, acc[i][1], 0, 0, 0);
      }
    }
  }

  #pragma unroll
  for (int i = 0; i < 6; ++i) {
    if (pv[i]) {
      #pragma unroll
      for (int nj = 0; nj < 2; ++nj) {
        const int oc = (nj ? nt1 : nt0) * 16 + mrow;
        const f32x4 a = acc[i][nj];
        float mx = fmaxf(fmaxf(a[0], a[1]), fmaxf(a[2], a[3]));
        float v = fminf(fmaxf(mx * ab[oc] + ab[256 + oc], -1.f), 1.f);
        const int m5 = (img0 + ilv[i]) * 9 + ppo_[i];
        size_t d = ((((((size_t)(m5 >> 6) * 2 + (oc >> 7)) * 4 + ((m5 >> 4) & 3)) * 4 +
                     ((oc >> 5) & 3)) * 4 + ((oc >> 3) & 3)) * 16 + (m5 & 15)) * 8 + (oc & 7);
        short hi = f2bf(v);
        outH[d] = hi;
        outL[d] = f2bf(v - bf2f(hi));
      }
    }
  }
}

// ------- fc MFMA GEMM: X and W direct from global (L2-hot), no LDS, no bars.
// OUTMODE 0: hi/lo frag for next fc (KC2); 1: fp32 row-major;
// OUTMODE 2: conv5 -> h5 frag (k1 = n*9 + m%9, m1 = m/9, KC2 chunks)
template <int KC, int OUTMODE, int KC2, int NALL>
__global__ __launch_bounds__(256, 4) void fc_mfma(
    const short* __restrict__ Xh, const short* __restrict__ Xl,
    const short* __restrict__ Wf, const float* __restrict__ ab,
    float* __restrict__ outF, short* __restrict__ outH, short* __restrict__ outL) {
  const int tid = threadIdx.x;
  const int bn = blockIdx.x, bm = blockIdx.y;
  const int lane = tid & 63, wv = tid >> 6;
  const int mrow = lane & 15, quad = lane >> 4;
  f32x4 acc[4];
  #pragma unroll
  for (int nt = 0; nt < 4; ++nt) acc[nt] = (f32x4){0.f, 0.f, 0.f, 0.f};

  for (int kc = 0; kc < KC; ++kc) {
    const short* xb = Xh + (((size_t)bm * KC + kc) * 4 + wv) * 2048;
    const short* xlb = Xl + (((size_t)bm * KC + kc) * 4 + wv) * 2048;
    const short* wb = Wf + ((size_t)bn * KC + kc) * 8192;
    #pragma unroll
    for (int ks = 0; ks < 4; ++ks) {
      const int ao = ((ks * 4 + quad) * 16 + mrow) * 8;
      const bf16x8 ah = *(const bf16x8*)&xb[ao];
      const bf16x8 al = *(const bf16x8*)&xlb[ao];
      #pragma unroll
      for (int nt = 0; nt < 4; ++nt) {
        const bf16x8 b = *(const bf16x8*)&wb[(((nt * 4 + ks) * 4 + quad) * 16 + mrow) * 8];
        acc[nt] = __builtin_amdgcn_mfma_f32_16x16x32_bf16(ah, b, acc[nt], 0, 0, 0);
        acc[nt] = __builtin_amdgcn_mfma_f32_16x16x32_bf16(al, b, acc[nt], 0, 0, 0);
      }
    }
  }

  #pragma unroll
  for (int nt = 0; nt < 4; ++nt) {
    const int n = bn * 64 + nt * 16 + mrow;
    const float A = ab[n], Bc = ab[NALL + n];
    #pragma unroll
    for (int r = 0; r < 4; ++r) {
      const int m = bm * 64 + wv * 16 + quad * 4 + r;
      float v = fminf(fmaxf(acc[nt][r] * A + Bc, -1.f), 1.f);
      if (OUTMODE == 0) {
        size_t d = (((((((size_t)(m >> 6) * KC2 + (n >> 7)) * 4 + ((m >> 4) & 3)) * 4 +
                       ((n >> 5) & 3)) * 4 + ((n >> 3) & 3)) * 16 + (m & 15))) * 8 + (n & 7);
        short hi = f2bf(v);
        outH[d] = hi;
        outL[d] = f2bf(v - bf2f(hi));
      } else if (OUTMODE == 1) {
        outF[(size_t)m * NALL + n] = v;
      } else {
        const int imgq = m / 9, p = m - imgq * 9;
        const int k1 = n * 9 + p;
        size_t d = ((((((size_t)(imgq >> 6) * KC2 + (k1 >> 7)) * 4 + ((imgq >> 4) & 3)) * 4 +
                     ((k1 >> 5) & 3)) * 4 + ((k1 >> 3) & 3)) * 16 + (imgq & 15)) * 8 + (k1 & 7);
        short hi = f2bf(v);
        outH[d] = hi;
        outL[d] = f2bf(v - bf2f(hi));
      }
    }
  }
}

// ---------------- FC3 (float4 inner loop) ----------------
__global__ __launch_bounds__(256) void fc3_kernel(
    const float* __restrict__ X, const float* __restrict__ W,
    const float* __restrict__ bias, float* __restrict__ out) {
  __shared__ float ws[512 * 10 + 16];
  for (int li = threadIdx.x; li < 5120; li += 256) {
    int n = li / 512, k = li - n * 512;
    ws[k * 10 + n] = W[li];
  }
  __syncthreads();
  const int il = threadIdx.x >> 4, n = threadIdx.x & 15;
  const int img = blockIdx.x * 16 + il;
  if (n < 10) {
    const float4* xp = (const float4*)(X + (size_t)img * 512);
    float s = 0.f;
    for (int k4 = 0; k4 < 128; ++k4) {
      const float4 xv = xp[k4];
      const int k = k4 * 4;
      s += xv.x * ws[k * 10 + n];
      s += xv.y * ws[(k + 1) * 10 + n];
      s += xv.z * ws[(k + 2) * 10 + n];
      s += xv.w * ws[(k + 3) * 10 + n];
    }
    out[img * 10 + n] = s + bias[n];
  }
}

// ---------------- launch ----------------
extern "C" void kernel_launch(void* const* d_in, const int* in_sizes, int n_in,
                              void* d_out, int out_size, void* d_ws, size_t ws_size,
                              hipStream_t stream) {
  (void)in_sizes; (void)n_in; (void)out_size; (void)ws_size;
  const float* x = (const float*)d_in[0];
  float* W = (float*)d_ws;

  // workspace layout (floats)
  float* wsc  = W + 0;                       // 2304
  float* ab   = W + 2304;                    // 4608
  float* fq3  = W + 6912;                    // 5120
  short* wb1  = (short*)(W + 12032);         // 1024 sh
  short* wb2  = (short*)(W + 12544);         // 51200 sh
  short* wb3  = (short*)(W + 38144);         // 73728 sh
  short* wb4  = (short*)(W + 75008);         // 294912 sh
  short* wb5  = (short*)(W + 222464);        // 65536 sh
  short* fqb1 = (short*)(W + 255232);        // 2359296 sh
  short* fqb2 = (short*)(W + 1434880);       // 524288 sh
  short* h1   = (short*)(W + 1697024);       // [1024][784][32] bf16
  short* h2   = (short*)(W + 14542080);      // [1024][196][64] bf16
  short* h3   = (short*)(W + 20964608);      // [1024][49][128] bf16
  short* h4h  = (short*)(W + 24175872);      // fc-frag bf16 hi (M=9216,K=256)
  short* h4l  = (short*)(W + 25355520);      // fc-frag bf16 lo
  short* h5h  = (short*)(W + 26535168);      // fc-frag bf16 hi (M=1024,K=2304)
  short* h5l  = (short*)(W + 27714816);      // fc-frag bf16 lo
  short* f1h  = (short*)(W + 28894464);      // fc-frag bf16 hi (M=1024,N=1024)
  short* f1l  = (short*)(W + 29418752);      // fc-frag bf16 lo
  float* f2   = W + 29943040;                // [1024][512]

  // 1) fused prep: scales + all repacks + fc3 dequant
  PrepArgs pa;
  const int widx[8] = {1, 7, 13, 19, 25, 31, 37, 43};
  short* pdst[8] = {wb1, wb2, wb3, wb4, wb5, fqb1, fqb2, nullptr};
  const int sco8[8] = {0, 32, 96, 224, 480, 736, 1760, 2272};
  const int cik8[8] = {25, 800, 576, 1152, 256, 2304, 1024, 512};
  const int co8[8] = {32, 64, 128, 256, 256, 1024, 512, 10};
  const int kind8[8] = {0, 1, 1, 2, 3, 3, 3, 4};
  const int KK8[8] = {25, 25, 9, 9, 1, 1, 1, 1};
  const int CI8[8] = {1, 32, 64, 128, 256, 2304, 1024, 512};
  const int OCCH8[8] = {32, 64, 64, 256, 256, 1024, 512, 10};
  const int KC8[8] = {1, 1, 1, 1, 2, 18, 8, 1};
  int cum = 0;
  for (int i = 0; i < 8; ++i) {
    pa.w[i] = (const float*)d_in[widx[i]];
    pa.dsth[i] = pdst[i];
    pa.sco[i] = sco8[i];
    pa.cik[i] = cik8[i];
    pa.kind[i] = kind8[i];
    pa.KK[i] = KK8[i];
    pa.CI[i] = CI8[i];
    pa.OCCH[i] = OCCH8[i];
    pa.KC[i] = KC8[i];
    pa.cum[i] = cum;
    cum += co8[i];
  }
  pa.cum[8] = cum;                  // 2282
  pa.dstf = fq3;
  pa.sc = wsc;
  hipLaunchKernelGGL(prep_all, dim3(cum), dim3(256), 0, stream, pa);

  // 2) fold BN (+ int-weight scale, all 7 layers)
  BnArgs ba;
  const int bbase[7] = {2, 8, 14, 20, 26, 32, 38};
  const int bc[7] = {32, 64, 128, 256, 256, 1024, 512};
  const int abo[7] = {0, 64, 192, 448, 960, 1472, 3520};
  int bcum = 0;
  for (int t = 0; t < 7; ++t) {
    for (int j = 0; j < 5; ++j) ba.p[t][j] = (const float*)d_in[bbase[t] + j];
    ba.C[t] = bc[t];
    ba.abo[t] = abo[t];
    ba.sco[t] = sco8[t];
    ba.cum[t] = bcum;
    bcum += bc[t];
  }
  ba.cum[7] = bcum;
  ba.ab = ab;
  ba.wsc = wsc;
  hipLaunchKernelGGL(bn_all, dim3((bcum + 255) / 256), dim3(256), 0, stream, ba);

  // 3) conv stack
  hipLaunchKernelGGL(conv1_mfma, dim3(1024), dim3(448), 0, stream,
                     x, wb1, ab + 0, h1);
  hipLaunchKernelGGL(conv2_half, dim3(2048), dim3(256), 0, stream,
                     h1, wb2, ab + 64, h2);
  hipLaunchKernelGGL(conv3_pad, dim3(512), dim3(256), 0, stream,
                     h2, wb3, ab + 192, h3);
  hipLaunchKernelGGL(conv4_mfma, dim3(512), dim3(512), 0, stream,
                     h3, wb4, ab + 448, h4h, h4l);
  hipLaunchKernelGGL((fc_mfma<2, 2, 18, 256>), dim3(4, 144), dim3(256), 0, stream,
                     h4h, h4l, wb5, ab + 960, nullptr, h5h, h5l);

  // 4) FC stack
  hipLaunchKernelGGL((fc_mfma<18, 0, 8, 1024>), dim3(16, 16), dim3(256), 0, stream,
                     h5h, h5l, fqb1, ab + 1472, nullptr, f1h, f1l);
  hipLaunchKernelGGL((fc_mfma<8, 1, 0, 512>), dim3(8, 16), dim3(256), 0, stream,
                     f1h, f1l, fqb2, ab + 3520, f2, nullptr, nullptr);
  hipLaunchKernelGGL(fc3_kernel, dim3(64), dim3(256), 0, stream,
                     f2, fq3, (const float*)d_in[44], (float*)d_out);
}

// Round 11
// 414.895 us; speedup vs baseline: 1.4657x; 1.4657x over previous
//
#include <hip/hip_runtime.h>
#include <hip/hip_bf16.h>
#include <math.h>

// ---------------------------------------------------------------------------
// BinaryCNN round 11: conv2/3/4 reverted to R9 LDS-dbuf weights (R10's
// B-from-global spilled the 128-AGPR accumulators to scratch: 274+273 MB
// FETCH/WRITE on conv3). fc_mfma keeps R10's no-LDS no-barrier form
// (16-reg acc -> no spill; verified correct in R10).
// ---------------------------------------------------------------------------

#define EPS 1e-5f

typedef __attribute__((ext_vector_type(8))) short bf16x8;
typedef __attribute__((ext_vector_type(4))) float f32x4;
typedef __attribute__((ext_vector_type(16))) float f32x16;
typedef __attribute__((ext_vector_type(4))) int i32x4;

__device__ __forceinline__ short f2bf(float f) {
  unsigned u = __builtin_bit_cast(unsigned, f);
  unsigned r = u + 0x7FFFu + ((u >> 16) & 1u);   // RNE
  return (short)(r >> 16);
}
__device__ __forceinline__ float bf2f(short h) {
  unsigned u = ((unsigned)(unsigned short)h) << 16;
  return __builtin_bit_cast(float, u);
}
__device__ __forceinline__ int swz2(int pin) {         // conv2: RS=32, S=4
  return (pin ^ (pin >> 2) ^ (pin >> 5)) & 3;
}
__device__ __forceinline__ int swz3(int pin) {         // conv3: RS=16, S=8
  return (pin ^ (pin >> 2) ^ (pin >> 4)) & 7;
}
__device__ __forceinline__ float qclip(float w, float s) {
  return fminf(fmaxf(rintf(w / s), -128.f), 127.f);
}

// ---------------- fused prep: scales + all weight repacks -------------------
struct PrepArgs {
  const float* w[8];
  short* dsth[8];
  float* dstf;
  float* sc;
  int sco[8];
  int cik[8];
  int kind[8];
  int KK[8];
  int CI[8];
  int OCCH[8];
  int KC[8];
  int cum[9];
};

__global__ __launch_bounds__(256) void prep_all(PrepArgs a) {
  int b = blockIdx.x;
  int t = 0;
  while (b >= a.cum[t + 1]) t++;
  int oc = b - a.cum[t];
  int cik = a.cik[t];
  const float* src = a.w[t] + (size_t)oc * cik;
  float m = 0.f;
  for (int i = threadIdx.x; i < cik; i += 256) m = fmaxf(m, fabsf(src[i]));
  #pragma unroll
  for (int o = 1; o < 64; o <<= 1) m = fmaxf(m, __shfl_xor(m, o));
  __shared__ float red[4];
  __shared__ float ssh;
  if ((threadIdx.x & 63) == 0) red[threadIdx.x >> 6] = m;
  __syncthreads();
  if (threadIdx.x == 0) {
    m = fmaxf(fmaxf(red[0], red[1]), fmaxf(red[2], red[3]));
    float s = fmaxf(m / 127.0f, 1e-8f);
    ssh = s;
    a.sc[a.sco[t] + oc] = s;
  }
  __syncthreads();
  const float s = ssh;
  const int kind = a.kind[t];
  short* dst = a.dsth[t];
  if (kind == 0) {
    for (int tt = threadIdx.x; tt < 32; tt += 256) {
      float q = (tt < 25) ? qclip(src[tt], s) : 0.f;
      dst[(((oc >> 4) * 4 + (tt >> 3)) * 16 + (oc & 15)) * 8 + (tt & 7)] = f2bf(q);
    }
  } else if (kind == 1) {
    const int KK = a.KK[t], CI = a.CI[t], OCCH = a.OCCH[t];
    const int NT32 = OCCH >> 5, KS16 = CI >> 4;
    const int chunk = oc / OCCH, ocl = oc - chunk * OCCH;
    const int nt = ocl >> 5, n32 = ocl & 31;
    for (int idx = threadIdx.x; idx < cik; idx += 256) {
      int ci = idx / KK, kk = idx - ci * KK;
      float q = qclip(src[idx], s);
      int ks = ci >> 4, hh = (ci >> 3) & 1, j = ci & 7;
      size_t d = ((((size_t)(chunk * KK + kk) * NT32 + nt) * KS16 + ks) * 64 +
                  hh * 32 + n32) * 8 + j;
      dst[d] = f2bf(q);
    }
  } else if (kind == 2) {
    const int KK = a.KK[t], CI = a.CI[t], OCCH = a.OCCH[t];
    const int NTC = OCCH >> 4, KS = CI >> 5;
    const int chunk = oc / OCCH, ocl = oc - chunk * OCCH;
    const int ntl = ocl >> 4, mr = ocl & 15;
    for (int idx = threadIdx.x; idx < cik; idx += 256) {
      int ci = idx / KK, kk = idx - ci * KK;
      float q = qclip(src[idx], s);
      int ks = ci >> 5, qq = (ci >> 3) & 3, j = ci & 7;
      size_t d = ((((((size_t)(chunk * KK + kk) * NTC + ntl) * KS + ks) * 4 + qq) *
                   16 + mr)) * 8 + j;
      dst[d] = f2bf(q);
    }
  } else if (kind == 3) {
    const int KC = a.KC[t];
    const int nblk = oc >> 6, ntl = (oc >> 4) & 3, mr = oc & 15;
    for (int k = threadIdx.x; k < cik; k += 256) {
      float q = qclip(src[k], s);
      size_t d = ((((((size_t)nblk * KC + (k >> 7)) * 4 + ntl) * 4 + ((k >> 5) & 3)) *
                   4 + ((k >> 3) & 3)) * 16 + mr) * 8 + (k & 7);
      dst[d] = f2bf(q);
    }
  } else {
    for (int k = threadIdx.x; k < cik; k += 256)
      a.dstf[(size_t)oc * cik + k] = qclip(src[k], s) * s;
  }
}

// ------ fold BN (+conv bias, + int-weight scale) into per-channel A,B ------
struct BnArgs {
  const float* p[7][5];   // b, g, be, mu, va
  const float* wsc;
  float* ab;
  int C[7];
  int abo[7];
  int sco[7];
  int cum[8];
};

__global__ __launch_bounds__(256) void bn_all(BnArgs a) {
  int i = blockIdx.x * 256 + threadIdx.x;
  if (i >= a.cum[7]) return;
  int t = 0;
  while (i >= a.cum[t + 1]) t++;
  int c = i - a.cum[t];
  float A = a.p[t][1][c] / sqrtf(a.p[t][4][c] + EPS);
  float B = (a.p[t][0][c] - a.p[t][3][c]) * A + a.p[t][2][c];
  a.ab[a.abo[t] + c] = A * a.wsc[a.sco[t] + c];
  a.ab[a.abo[t] + a.C[t] + c] = B;
}

// ---------------- conv1: padded source, per-pixel im2col, MFMA -------------
__global__ __launch_bounds__(448, 2) void conv1_mfma(
    const float* __restrict__ x, const short* __restrict__ wb1,
    const float* __restrict__ ab, short* __restrict__ out) {
  __shared__ __align__(16) float spad[1024];     // 32x32 zero-padded fp32
  __shared__ __align__(16) short sim[784 * 32];
  __shared__ __align__(16) short sw1[1024];
  const int tid = threadIdx.x;
  const int img = blockIdx.x;
  for (int i = tid; i < 1024; i += 448) spad[i] = 0.f;
  for (int i = tid; i < 1024; i += 448) sw1[i] = wb1[i];
  __syncthreads();
  for (int i = tid; i < 784; i += 448)
    spad[(i / 28 + 2) * 32 + (i % 28) + 2] = x[(size_t)img * 784 + i];
  __syncthreads();
  for (int p = tid; p < 784; p += 448) {
    const int py = p / 28, px = p - py * 28;
    const float* sp = &spad[py * 32 + px];
    short v[32];
    #pragma unroll
    for (int ty = 0; ty < 5; ++ty)
      #pragma unroll
      for (int tx = 0; tx < 5; ++tx)
        v[ty * 5 + tx] = f2bf(sp[ty * 32 + tx]);
    #pragma unroll
    for (int j = 25; j < 32; ++j) v[j] = 0;
    #pragma unroll
    for (int j = 0; j < 4; ++j)
      *(bf16x8*)&sim[p * 32 + j * 8] = *(const bf16x8*)&v[j * 8];
  }
  __syncthreads();
  const int lane = tid & 63, wv = tid >> 6;
  const int mrow = lane & 15, quad = lane >> 4;
  f32x4 acc[7][2];
  #pragma unroll
  for (int i = 0; i < 7; ++i) {
    acc[i][0] = (f32x4){0.f, 0.f, 0.f, 0.f};
    acc[i][1] = (f32x4){0.f, 0.f, 0.f, 0.f};
  }
  #pragma unroll
  for (int i = 0; i < 7; ++i) {
    const int mt = wv * 7 + i;
    const bf16x8 a = *(const bf16x8*)&sim[(mt * 16 + mrow) * 32 + quad * 8];
    #pragma unroll
    for (int nt = 0; nt < 2; ++nt) {
      const bf16x8 b = *(const bf16x8*)&sw1[(nt * 4 + quad) * 128 + mrow * 8];
      acc[i][nt] = __builtin_amdgcn_mfma_f32_16x16x32_bf16(a, b, acc[i][nt], 0, 0, 0);
    }
  }
  #pragma unroll
  for (int i = 0; i < 7; ++i) {
    const int mt = wv * 7 + i;
    #pragma unroll
    for (int nt = 0; nt < 2; ++nt) {
      const int oc = nt * 16 + mrow;
      const float A = ab[oc], Bc = ab[32 + oc];
      #pragma unroll
      for (int r = 0; r < 4; ++r) {
        const int p = mt * 16 + quad * 4 + r;
        float v = fminf(fmaxf(acc[i][nt][r] * A + Bc, -1.f), 1.f);
        out[((size_t)img * 784 + p) * 32 + oc] = f2bf(v);
      }
    }
  }
}

// -------- conv2: half-image, zero-halo padded LDS, dbuf weights (R9) --------
__global__ __launch_bounds__(256, 2) void conv2_half(
    const short* __restrict__ in, const short* __restrict__ wfrag,
    const float* __restrict__ ab, short* __restrict__ out) {
  constexpr int S = 4;                 // 16B blocks per pixel (32 ch)
  constexpr int RS = 32;               // padded row stride (cols)
  __shared__ __align__(16) short simg[18 * 32 * 32];   // 36864 B
  __shared__ __align__(16) short sw[2][10240];          // 2 x 20 KB
  const int tid = threadIdx.x;
  const int img = blockIdx.x >> 1, half = blockIdx.x & 1;
  const int lane = tid & 63, wv = tid >> 6;
  const int l31 = lane & 31, h = lane >> 5;

  // zero halo: 2 pad rows (full) + 4 pad cols x 16 valid rows = 128 px
  {
    const int padrow0 = half ? 16 : 0;
    const int vrow0 = half ? 0 : 2;
    for (int c = tid; c < 512; c += 256) {
      int hp = c >> 2, blk = c & 3;
      int pin;
      if (hp < 64) {
        pin = (padrow0 + (hp >> 5)) * RS + (hp & 31);
      } else {
        int r = (hp - 64) >> 2, cc = (hp - 64) & 3;
        int col = (cc < 2) ? cc : (28 + cc);
        pin = (vrow0 + r) * RS + col;
      }
      ((i32x4*)simg)[pin * S + blk] = (i32x4){0, 0, 0, 0};
    }
  }
  // stage 16 valid rows (global rows half*12 .. +15) at local rows vrow0..
  {
    const i32x4* gin = (const i32x4*)(in + ((size_t)img * 784 + half * 12 * 28) * 32);
    const int vrow0 = half ? 0 : 2;
    for (int c = tid; c < 1792; c += 256) {
      int ps = c >> 2, blk = c & 3;
      int pin = (vrow0 + ps / 28) * RS + ps % 28 + 2;
      ((i32x4*)simg)[pin * S + (blk ^ swz2(pin))] = gin[c];
    }
  }

  int pinb[4], ppb[4];
  bool uv2[4];
  #pragma unroll
  for (int i = 0; i < 4; ++i) {
    int u = wv + i * 4;
    uv2[i] = u < 13;
    int m = u * 32 + l31;
    int ppl = m >> 2, cd = m & 3;
    bool ok = uv2[i] && (ppl < 98);
    int pr = ppl / 14, pc = ppl - pr * 14;
    int ygl = (half * 7 + pr) * 2 + (cd >> 1);
    int yll = ygl - (half * 14 - 2);
    int xc = pc * 2 + (cd & 1) + 2;
    pinb[i] = ok ? (yll * RS + xc) : (2 * RS + 2);
    ppb[i] = u * 8;
  }

  f32x16 acc[4][2];
  #pragma unroll
  for (int i = 0; i < 4; ++i)
    #pragma unroll
    for (int nt = 0; nt < 2; ++nt)
      #pragma unroll
      for (int e = 0; e < 16; ++e) acc[i][nt][e] = 0.f;

  i32x4 wreg[5];
  {
    const i32x4* ws0 = (const i32x4*)wfrag;
    #pragma unroll
    for (int u2 = 0; u2 < 5; ++u2) wreg[u2] = ws0[tid + u2 * 256];
    #pragma unroll
    for (int u2 = 0; u2 < 5; ++u2) ((i32x4*)sw[0])[tid + u2 * 256] = wreg[u2];
  }

  for (int tg = 0; tg < 5; ++tg) {
    __syncthreads();
    if (tg < 4) {
      const i32x4* ws = (const i32x4*)(wfrag + (size_t)(tg + 1) * 10240);
      #pragma unroll
      for (int u2 = 0; u2 < 5; ++u2) wreg[u2] = ws[tid + u2 * 256];
    }
    const short* swb = sw[tg & 1];
    const int dy = tg - 2;
    #pragma unroll
    for (int tt = 0; tt < 5; ++tt) {
      const int tp = dy * RS + (tt - 2);
      int pin[4], sx4[4];
      #pragma unroll
      for (int i = 0; i < 4; ++i) {
        pin[i] = pinb[i] + tp;
        sx4[i] = swz2(pin[i]);
      }
      #pragma unroll
      for (int ks = 0; ks < 2; ++ks) {
        bf16x8 af[4];
        #pragma unroll
        for (int i = 0; i < 4; ++i)
          af[i] = *(const bf16x8*)&simg[pin[i] * 32 + (((ks * 2 + h) ^ sx4[i]) * 8)];
        #pragma unroll
        for (int nt = 0; nt < 2; ++nt) {
          const bf16x8 bf = *(const bf16x8*)&swb[(((tt * 2 + nt) * 2 + ks) * 64 + lane) * 8];
          #pragma unroll
          for (int i = 0; i < 4; ++i)
            acc[i][nt] = __builtin_amdgcn_mfma_f32_32x32x16_bf16(af[i], bf, acc[i][nt], 0, 0, 0);
        }
      }
    }
    if (tg < 4) {
      #pragma unroll
      for (int u2 = 0; u2 < 5; ++u2)
        ((i32x4*)sw[(tg + 1) & 1])[tid + u2 * 256] = wreg[u2];
    }
  }

  #pragma unroll
  for (int i = 0; i < 4; ++i) {
    #pragma unroll
    for (int nt = 0; nt < 2; ++nt) {
      const int oc = nt * 32 + l31;
      const float A = ab[oc], Bc = ab[64 + oc];
      #pragma unroll
      for (int g = 0; g < 4; ++g) {
        const int ppo = ppb[i] + 2 * g + h;
        if (uv2[i] && ppo < 98) {
          float mx = fmaxf(fmaxf(acc[i][nt][g * 4 + 0], acc[i][nt][g * 4 + 1]),
                           fmaxf(acc[i][nt][g * 4 + 2], acc[i][nt][g * 4 + 3]));
          float v = fminf(fmaxf(mx * A + Bc, -1.f), 1.f);
          out[((size_t)img * 196 + half * 98 + ppo) * 64 + oc] = f2bf(v);
        }
      }
    }
  }
}

// -------- conv3: 2 imgs, zero-halo 16x16 LDS, dbuf per-tap weights (R9) -----
__global__ __launch_bounds__(256, 2) void conv3_pad(
    const short* __restrict__ in, const short* __restrict__ wfrag,
    const float* __restrict__ ab, short* __restrict__ out) {
  constexpr int S = 8, RS = 16;
  __shared__ __align__(16) short simg[2 * 256 * 64];    // 65536 B
  __shared__ __align__(16) short sw[2][4096];           // 2 x 8 KB
  const int tid = threadIdx.x;
  const int img0 = blockIdx.x * 2;
  const int lane = tid & 63, wv = tid >> 6;
  const int l31 = lane & 31, h = lane >> 5;

  for (int c = tid; c < 960; c += 256) {
    int blk = c & 7, hp0 = c >> 3;
    int il = hp0 >= 60 ? 1 : 0, hp = hp0 - il * 60;
    int pin;
    if (hp < 32) pin = (hp >> 4) * 15 * RS + (hp & 15);
    else {
      int r = ((hp - 32) >> 1) + 1, cc = ((hp - 32) & 1) * 15;
      pin = r * RS + cc;
    }
    ((i32x4*)simg)[(il * 256 + pin) * S + blk] = (i32x4){0, 0, 0, 0};
  }
  {
    const i32x4* gin = (const i32x4*)(in + (size_t)img0 * 196 * 64);
    for (int c = tid; c < 3136; c += 256) {
      int il = c / 1568, r = c - il * 1568;
      int ps = r >> 3, blk = r & 7;
      int pin = (ps / 14 + 1) * RS + ps % 14 + 1;
      ((i32x4*)simg)[(il * 256 + pin) * S + (blk ^ swz3(pin))] = gin[c];
    }
  }

  int pinb[4], ppb[4], ilv[4];
  bool uv4[4];
  #pragma unroll
  for (int i = 0; i < 4; ++i) {
    int u = wv + i * 4;
    uv4[i] = u < 14;
    int uu = uv4[i] ? u : 0;
    int il = uu / 7, lt = uu - il * 7;
    int m = lt * 32 + l31, ppl = m >> 2, cd = m & 3;
    bool ok = uv4[i] && (ppl < 49);
    int py = ppl / 7, px = ppl - py * 7;
    int y = py * 2 + (cd >> 1), x = px * 2 + (cd & 1);
    pinb[i] = (ok ? ((y + 1) * RS + x + 1) : (RS + 1)) + il * 256;
    ilv[i] = il;
    ppb[i] = lt * 8;
  }

  f32x16 acc[4][2];
  #pragma unroll
  for (int i = 0; i < 4; ++i)
    #pragma unroll
    for (int nt = 0; nt < 2; ++nt)
      #pragma unroll
      for (int e = 0; e < 16; ++e) acc[i][nt][e] = 0.f;

  i32x4 wreg[2];
  {
    const i32x4* ws0 = (const i32x4*)wfrag;
    wreg[0] = ws0[tid];
    wreg[1] = ws0[tid + 256];
    ((i32x4*)sw[0])[tid] = wreg[0];
    ((i32x4*)sw[0])[tid + 256] = wreg[1];
  }

  for (int s = 0; s < 18; ++s) {
    __syncthreads();
    if (s < 17) {
      const i32x4* ws = (const i32x4*)(wfrag + (size_t)(s + 1) * 4096);
      wreg[0] = ws[tid];
      wreg[1] = ws[tid + 256];
    }
    const short* swb = sw[s & 1];
    const int t = s % 9;
    const int tp = (t / 3 - 1) * RS + (t % 3 - 1);
    int pin[4], sx4[4];
    #pragma unroll
    for (int i = 0; i < 4; ++i) {
      pin[i] = pinb[i] + tp;
      sx4[i] = swz3(pin[i]);
    }
    #pragma unroll
    for (int ks = 0; ks < 4; ++ks) {
      bf16x8 af[4];
      #pragma unroll
      for (int i = 0; i < 4; ++i)
        af[i] = *(const bf16x8*)&simg[pin[i] * 64 + (((ks * 2 + h) ^ sx4[i]) * 8)];
      #pragma unroll
      for (int nt = 0; nt < 2; ++nt) {
        const bf16x8 bf = *(const bf16x8*)&swb[((nt * 4 + ks) * 64 + lane) * 8];
        #pragma unroll
        for (int i = 0; i < 4; ++i)
          acc[i][nt] = __builtin_amdgcn_mfma_f32_32x32x16_bf16(af[i], bf, acc[i][nt], 0, 0, 0);
      }
    }
    if (s < 17) {
      ((i32x4*)sw[(s + 1) & 1])[tid] = wreg[0];
      ((i32x4*)sw[(s + 1) & 1])[tid + 256] = wreg[1];
    }
    if (t == 8) {
      const int ch = s / 9;
      #pragma unroll
      for (int i = 0; i < 4; ++i) {
        #pragma unroll
        for (int nt = 0; nt < 2; ++nt) {
          const int oc = ch * 64 + nt * 32 + l31;
          const float A = ab[oc], Bc = ab[128 + oc];
          #pragma unroll
          for (int g = 0; g < 4; ++g) {
            const int ppo = ppb[i] + 2 * g + h;
            if (uv4[i] && ppo < 49) {
              float mx = fmaxf(fmaxf(acc[i][nt][g * 4 + 0], acc[i][nt][g * 4 + 1]),
                               fmaxf(acc[i][nt][g * 4 + 2], acc[i][nt][g * 4 + 3]));
              float v = fminf(fmaxf(mx * A + Bc, -1.f), 1.f);
              out[((size_t)(img0 + ilv[i]) * 49 + ppo) * 128 + oc] = f2bf(v);
            }
          }
          #pragma unroll
          for (int e = 0; e < 16; ++e) acc[i][nt][e] = 0.f;
        }
      }
    }
  }
}

// -------- conv4: tap-outer dbuf weights (R9); emits h4 hi/lo fc-frag --------
__global__ __launch_bounds__(512, 2) void conv4_mfma(
    const short* __restrict__ in,      // h3 bf16 [img][49][128]
    const short* __restrict__ wfrag,   // [9][16][4][4][16][8]
    const float* __restrict__ ab,
    short* __restrict__ outH, short* __restrict__ outL) {
  constexpr int S = 16, NPIX = 49, PP = 9;
  __shared__ __align__(16) short simg[2 * NPIX * 128];
  __shared__ __align__(16) short swb[2][32768];
  const int tid = threadIdx.x;
  const int img0 = blockIdx.x * 2;
  const int lane = tid & 63, wv = tid >> 6;
  const int mrow = lane & 15, quad = lane >> 4;

  {
    const i32x4* gsrc = (const i32x4*)(in + (size_t)img0 * NPIX * 128);
    for (int c = tid; c < 2 * NPIX * S; c += 512) {
      int il = c / (NPIX * S);
      int r = c - il * (NPIX * S);
      int pix = r >> 4, blk = r & 15;
      ((i32x4*)simg)[il * NPIX * S + pix * S + (blk ^ (pix & 15))] = gsrc[c];
    }
    for (int u = tid; u < 4096; u += 512)
      ((i32x4*)swb[0])[u] = ((const i32x4*)wfrag)[u];
  }

  int yy[6], xx[6], ibs[6], ppo_[6], ilv[6];
  bool rv[6], pv[6];
  #pragma unroll
  for (int i = 0; i < 6; ++i) {
    int il = i / 3, lt = i - il * 3;
    int m = lt * 16 + mrow;
    int pp = m >> 2, cd = m & 3;
    rv[i] = pp < PP;
    int py = pp / 3, px = pp - py * 3;
    yy[i] = py * 2 + (cd >> 1);
    xx[i] = px * 2 + (cd & 1);
    ibs[i] = il * NPIX * S;
    ilv[i] = il;
    ppo_[i] = lt * 4 + quad;
    pv[i] = ppo_[i] < PP;
  }
  const int nt0 = wv, nt1 = wv + 8;
  f32x4 acc[6][2];
  #pragma unroll
  for (int i = 0; i < 6; ++i) {
    acc[i][0] = (f32x4){0.f, 0.f, 0.f, 0.f};
    acc[i][1] = (f32x4){0.f, 0.f, 0.f, 0.f};
  }
  __syncthreads();

  int dy = -1, dx = -1;
  for (int t = 0; t < 9; ++t) {
    const int buf = t & 1;
    if (t < 8) {
      const i32x4* wsrc = (const i32x4*)(wfrag + (size_t)(t + 1) * 32768);
      for (int u = tid; u < 4096; u += 512) ((i32x4*)swb[buf ^ 1])[u] = wsrc[u];
    }
    #pragma unroll
    for (int ks = 0; ks < 4; ++ks) {
      bf16x8 af[6];
      #pragma unroll
      for (int i = 0; i < 6; ++i) {
        int iy = yy[i] + dy, ix = xx[i] + dx;
        bool ok = rv[i] && (unsigned)iy < 7u && (unsigned)ix < 7u;
        int pin = iy * 7 + ix;
        int blk = (ks * 4 + quad) ^ (pin & 15);
        af[i] = ok ? *(const bf16x8*)&simg[(ibs[i] + pin * S + blk) * 8]
                   : (bf16x8){0, 0, 0, 0, 0, 0, 0, 0};
      }
      const bf16x8 b0 = *(const bf16x8*)&swb[buf][((nt0 * 4 + ks) * 4 + quad) * 128 + mrow * 8];
      const bf16x8 b1 = *(const bf16x8*)&swb[buf][((nt1 * 4 + ks) * 4 + quad) * 128 + mrow * 8];
      #pragma unroll
      for (int i = 0; i < 6; ++i) {
        acc[i][0] = __builtin_amdgcn_mfma_f32_16x16x32_bf16(af[i], b0, acc[i][0], 0, 0, 0);
        acc[i][1] = __builtin_amdgcn_mfma_f32_16x16x32_bf16(af[i], b1, acc[i][1], 0, 0, 0);
      }
    }
    dx++;
    if (dx == 2) { dx = -1; dy++; }
    __syncthreads();
  }

  #pragma unroll
  for (int i = 0; i < 6; ++i) {
    if (pv[i]) {
      #pragma unroll
      for (int nj = 0; nj < 2; ++nj) {
        const int oc = (nj ? nt1 : nt0) * 16 + mrow;
        const f32x4 a = acc[i][nj];
        float mx = fmaxf(fmaxf(a[0], a[1]), fmaxf(a[2], a[3]));
        float v = fminf(fmaxf(mx * ab[oc] + ab[256 + oc], -1.f), 1.f);
        const int m5 = (img0 + ilv[i]) * 9 + ppo_[i];
        size_t d = ((((((size_t)(m5 >> 6) * 2 + (oc >> 7)) * 4 + ((m5 >> 4) & 3)) * 4 +
                     ((oc >> 5) & 3)) * 4 + ((oc >> 3) & 3)) * 16 + (m5 & 15)) * 8 + (oc & 7);
        short hi = f2bf(v);
        outH[d] = hi;
        outL[d] = f2bf(v - bf2f(hi));
      }
    }
  }
}

// ------- fc MFMA GEMM: X and W direct from global (L2-hot), no LDS, no bars.
// (R10 version — 16-reg acc, no spill, verified correct.)
// OUTMODE 0: hi/lo frag for next fc (KC2); 1: fp32 row-major;
// OUTMODE 2: conv5 -> h5 frag (k1 = n*9 + m%9, m1 = m/9, KC2 chunks)
template <int KC, int OUTMODE, int KC2, int NALL>
__global__ __launch_bounds__(256, 4) void fc_mfma(
    const short* __restrict__ Xh, const short* __restrict__ Xl,
    const short* __restrict__ Wf, const float* __restrict__ ab,
    float* __restrict__ outF, short* __restrict__ outH, short* __restrict__ outL) {
  const int tid = threadIdx.x;
  const int bn = blockIdx.x, bm = blockIdx.y;
  const int lane = tid & 63, wv = tid >> 6;
  const int mrow = lane & 15, quad = lane >> 4;
  f32x4 acc[4];
  #pragma unroll
  for (int nt = 0; nt < 4; ++nt) acc[nt] = (f32x4){0.f, 0.f, 0.f, 0.f};

  for (int kc = 0; kc < KC; ++kc) {
    const short* xb = Xh + (((size_t)bm * KC + kc) * 4 + wv) * 2048;
    const short* xlb = Xl + (((size_t)bm * KC + kc) * 4 + wv) * 2048;
    const short* wb = Wf + ((size_t)bn * KC + kc) * 8192;
    #pragma unroll
    for (int ks = 0; ks < 4; ++ks) {
      const int ao = ((ks * 4 + quad) * 16 + mrow) * 8;
      const bf16x8 ah = *(const bf16x8*)&xb[ao];
      const bf16x8 al = *(const bf16x8*)&xlb[ao];
      #pragma unroll
      for (int nt = 0; nt < 4; ++nt) {
        const bf16x8 b = *(const bf16x8*)&wb[(((nt * 4 + ks) * 4 + quad) * 16 + mrow) * 8];
        acc[nt] = __builtin_amdgcn_mfma_f32_16x16x32_bf16(ah, b, acc[nt], 0, 0, 0);
        acc[nt] = __builtin_amdgcn_mfma_f32_16x16x32_bf16(al, b, acc[nt], 0, 0, 0);
      }
    }
  }

  #pragma unroll
  for (int nt = 0; nt < 4; ++nt) {
    const int n = bn * 64 + nt * 16 + mrow;
    const float A = ab[n], Bc = ab[NALL + n];
    #pragma unroll
    for (int r = 0; r < 4; ++r) {
      const int m = bm * 64 + wv * 16 + quad * 4 + r;
      float v = fminf(fmaxf(acc[nt][r] * A + Bc, -1.f), 1.f);
      if (OUTMODE == 0) {
        size_t d = (((((((size_t)(m >> 6) * KC2 + (n >> 7)) * 4 + ((m >> 4) & 3)) * 4 +
                       ((n >> 5) & 3)) * 4 + ((n >> 3) & 3)) * 16 + (m & 15))) * 8 + (n & 7);
        short hi = f2bf(v);
        outH[d] = hi;
        outL[d] = f2bf(v - bf2f(hi));
      } else if (OUTMODE == 1) {
        outF[(size_t)m * NALL + n] = v;
      } else {
        const int imgq = m / 9, p = m - imgq * 9;
        const int k1 = n * 9 + p;
        size_t d = ((((((size_t)(imgq >> 6) * KC2 + (k1 >> 7)) * 4 + ((imgq >> 4) & 3)) * 4 +
                     ((k1 >> 5) & 3)) * 4 + ((k1 >> 3) & 3)) * 16 + (imgq & 15)) * 8 + (k1 & 7);
        short hi = f2bf(v);
        outH[d] = hi;
        outL[d] = f2bf(v - bf2f(hi));
      }
    }
  }
}

// ---------------- FC3 (float4 inner loop) ----------------
__global__ __launch_bounds__(256) void fc3_kernel(
    const float* __restrict__ X, const float* __restrict__ W,
    const float* __restrict__ bias, float* __restrict__ out) {
  __shared__ float ws[512 * 10 + 16];
  for (int li = threadIdx.x; li < 5120; li += 256) {
    int n = li / 512, k = li - n * 512;
    ws[k * 10 + n] = W[li];
  }
  __syncthreads();
  const int il = threadIdx.x >> 4, n = threadIdx.x & 15;
  const int img = blockIdx.x * 16 + il;
  if (n < 10) {
    const float4* xp = (const float4*)(X + (size_t)img * 512);
    float s = 0.f;
    for (int k4 = 0; k4 < 128; ++k4) {
      const float4 xv = xp[k4];
      const int k = k4 * 4;
      s += xv.x * ws[k * 10 + n];
      s += xv.y * ws[(k + 1) * 10 + n];
      s += xv.z * ws[(k + 2) * 10 + n];
      s += xv.w * ws[(k + 3) * 10 + n];
    }
    out[img * 10 + n] = s + bias[n];
  }
}

// ---------------- launch ----------------
extern "C" void kernel_launch(void* const* d_in, const int* in_sizes, int n_in,
                              void* d_out, int out_size, void* d_ws, size_t ws_size,
                              hipStream_t stream) {
  (void)in_sizes; (void)n_in; (void)out_size; (void)ws_size;
  const float* x = (const float*)d_in[0];
  float* W = (float*)d_ws;

  // workspace layout (floats)
  float* wsc  = W + 0;                       // 2304
  float* ab   = W + 2304;                    // 4608
  float* fq3  = W + 6912;                    // 5120
  short* wb1  = (short*)(W + 12032);         // 1024 sh
  short* wb2  = (short*)(W + 12544);         // 51200 sh
  short* wb3  = (short*)(W + 38144);         // 73728 sh
  short* wb4  = (short*)(W + 75008);         // 294912 sh
  short* wb5  = (short*)(W + 222464);        // 65536 sh
  short* fqb1 = (short*)(W + 255232);        // 2359296 sh
  short* fqb2 = (short*)(W + 1434880);       // 524288 sh
  short* h1   = (short*)(W + 1697024);       // [1024][784][32] bf16
  short* h2   = (short*)(W + 14542080);      // [1024][196][64] bf16
  short* h3   = (short*)(W + 20964608);      // [1024][49][128] bf16
  short* h4h  = (short*)(W + 24175872);      // fc-frag bf16 hi (M=9216,K=256)
  short* h4l  = (short*)(W + 25355520);      // fc-frag bf16 lo
  short* h5h  = (short*)(W + 26535168);      // fc-frag bf16 hi (M=1024,K=2304)
  short* h5l  = (short*)(W + 27714816);      // fc-frag bf16 lo
  short* f1h  = (short*)(W + 28894464);      // fc-frag bf16 hi (M=1024,N=1024)
  short* f1l  = (short*)(W + 29418752);      // fc-frag bf16 lo
  float* f2   = W + 29943040;                // [1024][512]

  // 1) fused prep: scales + all repacks + fc3 dequant
  PrepArgs pa;
  const int widx[8] = {1, 7, 13, 19, 25, 31, 37, 43};
  short* pdst[8] = {wb1, wb2, wb3, wb4, wb5, fqb1, fqb2, nullptr};
  const int sco8[8] = {0, 32, 96, 224, 480, 736, 1760, 2272};
  const int cik8[8] = {25, 800, 576, 1152, 256, 2304, 1024, 512};
  const int co8[8] = {32, 64, 128, 256, 256, 1024, 512, 10};
  const int kind8[8] = {0, 1, 1, 2, 3, 3, 3, 4};
  const int KK8[8] = {25, 25, 9, 9, 1, 1, 1, 1};
  const int CI8[8] = {1, 32, 64, 128, 256, 2304, 1024, 512};
  const int OCCH8[8] = {32, 64, 64, 256, 256, 1024, 512, 10};
  const int KC8[8] = {1, 1, 1, 1, 2, 18, 8, 1};
  int cum = 0;
  for (int i = 0; i < 8; ++i) {
    pa.w[i] = (const float*)d_in[widx[i]];
    pa.dsth[i] = pdst[i];
    pa.sco[i] = sco8[i];
    pa.cik[i] = cik8[i];
    pa.kind[i] = kind8[i];
    pa.KK[i] = KK8[i];
    pa.CI[i] = CI8[i];
    pa.OCCH[i] = OCCH8[i];
    pa.KC[i] = KC8[i];
    pa.cum[i] = cum;
    cum += co8[i];
  }
  pa.cum[8] = cum;                  // 2282
  pa.dstf = fq3;
  pa.sc = wsc;
  hipLaunchKernelGGL(prep_all, dim3(cum), dim3(256), 0, stream, pa);

  // 2) fold BN (+ int-weight scale, all 7 layers)
  BnArgs ba;
  const int bbase[7] = {2, 8, 14, 20, 26, 32, 38};
  const int bc[7] = {32, 64, 128, 256, 256, 1024, 512};
  const int abo[7] = {0, 64, 192, 448, 960, 1472, 3520};
  int bcum = 0;
  for (int t = 0; t < 7; ++t) {
    for (int j = 0; j < 5; ++j) ba.p[t][j] = (const float*)d_in[bbase[t] + j];
    ba.C[t] = bc[t];
    ba.abo[t] = abo[t];
    ba.sco[t] = sco8[t];
    ba.cum[t] = bcum;
    bcum += bc[t];
  }
  ba.cum[7] = bcum;
  ba.ab = ab;
  ba.wsc = wsc;
  hipLaunchKernelGGL(bn_all, dim3((bcum + 255) / 256), dim3(256), 0, stream, ba);

  // 3) conv stack
  hipLaunchKernelGGL(conv1_mfma, dim3(1024), dim3(448), 0, stream,
                     x, wb1, ab + 0, h1);
  hipLaunchKernelGGL(conv2_half, dim3(2048), dim3(256), 0, stream,
                     h1, wb2, ab + 64, h2);
  hipLaunchKernelGGL(conv3_pad, dim3(512), dim3(256), 0, stream,
                     h2, wb3, ab + 192, h3);
  hipLaunchKernelGGL(conv4_mfma, dim3(512), dim3(512), 0, stream,
                     h3, wb4, ab + 448, h4h, h4l);
  hipLaunchKernelGGL((fc_mfma<2, 2, 18, 256>), dim3(4, 144), dim3(256), 0, stream,
                     h4h, h4l, wb5, ab + 960, nullptr, h5h, h5l);

  // 4) FC stack
  hipLaunchKernelGGL((fc_mfma<18, 0, 8, 1024>), dim3(16, 16), dim3(256), 0, stream,
                     h5h, h5l, fqb1, ab + 1472, nullptr, f1h, f1l);
  hipLaunchKernelGGL((fc_mfma<8, 1, 0, 512>), dim3(8, 16), dim3(256), 0, stream,
                     f1h, f1l, fqb2, ab + 3520, f2, nullptr, nullptr);
  hipLaunchKernelGGL(fc3_kernel, dim3(64), dim3(256), 0, stream,
                     f2, fq3, (const float*)d_in[44], (float*)d_out);
}

// Round 12
// 411.295 us; speedup vs baseline: 1.4785x; 1.0088x over previous
//
#include <hip/hip_runtime.h>
#include <hip/hip_bf16.h>
#include <math.h>

// ---------------------------------------------------------------------------
// BinaryCNN round 12: fc1/fc2 K-split partials (fc1 was 1 blk/CU = 12.5%
// occupancy, latency-bound on L2 with no LDS; fc2 was 0.5 blk/CU).
// fc1: grid(16,16,3) KCP=6 -> fp32 partials -> combine(bn+ht+frag hi/lo).
// fc2: grid(8,16,4) KCP=2 -> fp32 partials -> combine(bn+ht+fp32).
// Everything else identical to R11 (conv2/3/4 R9 LDS-dbuf, conv5 no-LDS GEMM).
// ---------------------------------------------------------------------------

#define EPS 1e-5f

typedef __attribute__((ext_vector_type(8))) short bf16x8;
typedef __attribute__((ext_vector_type(4))) float f32x4;
typedef __attribute__((ext_vector_type(16))) float f32x16;
typedef __attribute__((ext_vector_type(4))) int i32x4;

__device__ __forceinline__ short f2bf(float f) {
  unsigned u = __builtin_bit_cast(unsigned, f);
  unsigned r = u + 0x7FFFu + ((u >> 16) & 1u);   // RNE
  return (short)(r >> 16);
}
__device__ __forceinline__ float bf2f(short h) {
  unsigned u = ((unsigned)(unsigned short)h) << 16;
  return __builtin_bit_cast(float, u);
}
__device__ __forceinline__ int swz2(int pin) {         // conv2: RS=32, S=4
  return (pin ^ (pin >> 2) ^ (pin >> 5)) & 3;
}
__device__ __forceinline__ int swz3(int pin) {         // conv3: RS=16, S=8
  return (pin ^ (pin >> 2) ^ (pin >> 4)) & 7;
}
__device__ __forceinline__ float qclip(float w, float s) {
  return fminf(fmaxf(rintf(w / s), -128.f), 127.f);
}

// ---------------- fused prep: scales + all weight repacks -------------------
struct PrepArgs {
  const float* w[8];
  short* dsth[8];
  float* dstf;
  float* sc;
  int sco[8];
  int cik[8];
  int kind[8];
  int KK[8];
  int CI[8];
  int OCCH[8];
  int KC[8];
  int cum[9];
};

__global__ __launch_bounds__(256) void prep_all(PrepArgs a) {
  int b = blockIdx.x;
  int t = 0;
  while (b >= a.cum[t + 1]) t++;
  int oc = b - a.cum[t];
  int cik = a.cik[t];
  const float* src = a.w[t] + (size_t)oc * cik;
  float m = 0.f;
  for (int i = threadIdx.x; i < cik; i += 256) m = fmaxf(m, fabsf(src[i]));
  #pragma unroll
  for (int o = 1; o < 64; o <<= 1) m = fmaxf(m, __shfl_xor(m, o));
  __shared__ float red[4];
  __shared__ float ssh;
  if ((threadIdx.x & 63) == 0) red[threadIdx.x >> 6] = m;
  __syncthreads();
  if (threadIdx.x == 0) {
    m = fmaxf(fmaxf(red[0], red[1]), fmaxf(red[2], red[3]));
    float s = fmaxf(m / 127.0f, 1e-8f);
    ssh = s;
    a.sc[a.sco[t] + oc] = s;
  }
  __syncthreads();
  const float s = ssh;
  const int kind = a.kind[t];
  short* dst = a.dsth[t];
  if (kind == 0) {
    for (int tt = threadIdx.x; tt < 32; tt += 256) {
      float q = (tt < 25) ? qclip(src[tt], s) : 0.f;
      dst[(((oc >> 4) * 4 + (tt >> 3)) * 16 + (oc & 15)) * 8 + (tt & 7)] = f2bf(q);
    }
  } else if (kind == 1) {
    const int KK = a.KK[t], CI = a.CI[t], OCCH = a.OCCH[t];
    const int NT32 = OCCH >> 5, KS16 = CI >> 4;
    const int chunk = oc / OCCH, ocl = oc - chunk * OCCH;
    const int nt = ocl >> 5, n32 = ocl & 31;
    for (int idx = threadIdx.x; idx < cik; idx += 256) {
      int ci = idx / KK, kk = idx - ci * KK;
      float q = qclip(src[idx], s);
      int ks = ci >> 4, hh = (ci >> 3) & 1, j = ci & 7;
      size_t d = ((((size_t)(chunk * KK + kk) * NT32 + nt) * KS16 + ks) * 64 +
                  hh * 32 + n32) * 8 + j;
      dst[d] = f2bf(q);
    }
  } else if (kind == 2) {
    const int KK = a.KK[t], CI = a.CI[t], OCCH = a.OCCH[t];
    const int NTC = OCCH >> 4, KS = CI >> 5;
    const int chunk = oc / OCCH, ocl = oc - chunk * OCCH;
    const int ntl = ocl >> 4, mr = ocl & 15;
    for (int idx = threadIdx.x; idx < cik; idx += 256) {
      int ci = idx / KK, kk = idx - ci * KK;
      float q = qclip(src[idx], s);
      int ks = ci >> 5, qq = (ci >> 3) & 3, j = ci & 7;
      size_t d = ((((((size_t)(chunk * KK + kk) * NTC + ntl) * KS + ks) * 4 + qq) *
                   16 + mr)) * 8 + j;
      dst[d] = f2bf(q);
    }
  } else if (kind == 3) {
    const int KC = a.KC[t];
    const int nblk = oc >> 6, ntl = (oc >> 4) & 3, mr = oc & 15;
    for (int k = threadIdx.x; k < cik; k += 256) {
      float q = qclip(src[k], s);
      size_t d = ((((((size_t)nblk * KC + (k >> 7)) * 4 + ntl) * 4 + ((k >> 5) & 3)) *
                   4 + ((k >> 3) & 3)) * 16 + mr) * 8 + (k & 7);
      dst[d] = f2bf(q);
    }
  } else {
    for (int k = threadIdx.x; k < cik; k += 256)
      a.dstf[(size_t)oc * cik + k] = qclip(src[k], s) * s;
  }
}

// ------ fold BN (+conv bias, + int-weight scale) into per-channel A,B ------
struct BnArgs {
  const float* p[7][5];   // b, g, be, mu, va
  const float* wsc;
  float* ab;
  int C[7];
  int abo[7];
  int sco[7];
  int cum[8];
};

__global__ __launch_bounds__(256) void bn_all(BnArgs a) {
  int i = blockIdx.x * 256 + threadIdx.x;
  if (i >= a.cum[7]) return;
  int t = 0;
  while (i >= a.cum[t + 1]) t++;
  int c = i - a.cum[t];
  float A = a.p[t][1][c] / sqrtf(a.p[t][4][c] + EPS);
  float B = (a.p[t][0][c] - a.p[t][3][c]) * A + a.p[t][2][c];
  a.ab[a.abo[t] + c] = A * a.wsc[a.sco[t] + c];
  a.ab[a.abo[t] + a.C[t] + c] = B;
}

// ---------------- conv1: padded source, per-pixel im2col, MFMA -------------
__global__ __launch_bounds__(448, 2) void conv1_mfma(
    const float* __restrict__ x, const short* __restrict__ wb1,
    const float* __restrict__ ab, short* __restrict__ out) {
  __shared__ __align__(16) float spad[1024];     // 32x32 zero-padded fp32
  __shared__ __align__(16) short sim[784 * 32];
  __shared__ __align__(16) short sw1[1024];
  const int tid = threadIdx.x;
  const int img = blockIdx.x;
  for (int i = tid; i < 1024; i += 448) spad[i] = 0.f;
  for (int i = tid; i < 1024; i += 448) sw1[i] = wb1[i];
  __syncthreads();
  for (int i = tid; i < 784; i += 448)
    spad[(i / 28 + 2) * 32 + (i % 28) + 2] = x[(size_t)img * 784 + i];
  __syncthreads();
  for (int p = tid; p < 784; p += 448) {
    const int py = p / 28, px = p - py * 28;
    const float* sp = &spad[py * 32 + px];
    short v[32];
    #pragma unroll
    for (int ty = 0; ty < 5; ++ty)
      #pragma unroll
      for (int tx = 0; tx < 5; ++tx)
        v[ty * 5 + tx] = f2bf(sp[ty * 32 + tx]);
    #pragma unroll
    for (int j = 25; j < 32; ++j) v[j] = 0;
    #pragma unroll
    for (int j = 0; j < 4; ++j)
      *(bf16x8*)&sim[p * 32 + j * 8] = *(const bf16x8*)&v[j * 8];
  }
  __syncthreads();
  const int lane = tid & 63, wv = tid >> 6;
  const int mrow = lane & 15, quad = lane >> 4;
  f32x4 acc[7][2];
  #pragma unroll
  for (int i = 0; i < 7; ++i) {
    acc[i][0] = (f32x4){0.f, 0.f, 0.f, 0.f};
    acc[i][1] = (f32x4){0.f, 0.f, 0.f, 0.f};
  }
  #pragma unroll
  for (int i = 0; i < 7; ++i) {
    const int mt = wv * 7 + i;
    const bf16x8 a = *(const bf16x8*)&sim[(mt * 16 + mrow) * 32 + quad * 8];
    #pragma unroll
    for (int nt = 0; nt < 2; ++nt) {
      const bf16x8 b = *(const bf16x8*)&sw1[(nt * 4 + quad) * 128 + mrow * 8];
      acc[i][nt] = __builtin_amdgcn_mfma_f32_16x16x32_bf16(a, b, acc[i][nt], 0, 0, 0);
    }
  }
  #pragma unroll
  for (int i = 0; i < 7; ++i) {
    const int mt = wv * 7 + i;
    #pragma unroll
    for (int nt = 0; nt < 2; ++nt) {
      const int oc = nt * 16 + mrow;
      const float A = ab[oc], Bc = ab[32 + oc];
      #pragma unroll
      for (int r = 0; r < 4; ++r) {
        const int p = mt * 16 + quad * 4 + r;
        float v = fminf(fmaxf(acc[i][nt][r] * A + Bc, -1.f), 1.f);
        out[((size_t)img * 784 + p) * 32 + oc] = f2bf(v);
      }
    }
  }
}

// -------- conv2: half-image, zero-halo padded LDS, dbuf weights (R9) --------
__global__ __launch_bounds__(256, 2) void conv2_half(
    const short* __restrict__ in, const short* __restrict__ wfrag,
    const float* __restrict__ ab, short* __restrict__ out) {
  constexpr int S = 4;                 // 16B blocks per pixel (32 ch)
  constexpr int RS = 32;               // padded row stride (cols)
  __shared__ __align__(16) short simg[18 * 32 * 32];   // 36864 B
  __shared__ __align__(16) short sw[2][10240];          // 2 x 20 KB
  const int tid = threadIdx.x;
  const int img = blockIdx.x >> 1, half = blockIdx.x & 1;
  const int lane = tid & 63, wv = tid >> 6;
  const int l31 = lane & 31, h = lane >> 5;

  {
    const int padrow0 = half ? 16 : 0;
    const int vrow0 = half ? 0 : 2;
    for (int c = tid; c < 512; c += 256) {
      int hp = c >> 2, blk = c & 3;
      int pin;
      if (hp < 64) {
        pin = (padrow0 + (hp >> 5)) * RS + (hp & 31);
      } else {
        int r = (hp - 64) >> 2, cc = (hp - 64) & 3;
        int col = (cc < 2) ? cc : (28 + cc);
        pin = (vrow0 + r) * RS + col;
      }
      ((i32x4*)simg)[pin * S + blk] = (i32x4){0, 0, 0, 0};
    }
  }
  {
    const i32x4* gin = (const i32x4*)(in + ((size_t)img * 784 + half * 12 * 28) * 32);
    const int vrow0 = half ? 0 : 2;
    for (int c = tid; c < 1792; c += 256) {
      int ps = c >> 2, blk = c & 3;
      int pin = (vrow0 + ps / 28) * RS + ps % 28 + 2;
      ((i32x4*)simg)[pin * S + (blk ^ swz2(pin))] = gin[c];
    }
  }

  int pinb[4], ppb[4];
  bool uv2[4];
  #pragma unroll
  for (int i = 0; i < 4; ++i) {
    int u = wv + i * 4;
    uv2[i] = u < 13;
    int m = u * 32 + l31;
    int ppl = m >> 2, cd = m & 3;
    bool ok = uv2[i] && (ppl < 98);
    int pr = ppl / 14, pc = ppl - pr * 14;
    int ygl = (half * 7 + pr) * 2 + (cd >> 1);
    int yll = ygl - (half * 14 - 2);
    int xc = pc * 2 + (cd & 1) + 2;
    pinb[i] = ok ? (yll * RS + xc) : (2 * RS + 2);
    ppb[i] = u * 8;
  }

  f32x16 acc[4][2];
  #pragma unroll
  for (int i = 0; i < 4; ++i)
    #pragma unroll
    for (int nt = 0; nt < 2; ++nt)
      #pragma unroll
      for (int e = 0; e < 16; ++e) acc[i][nt][e] = 0.f;

  i32x4 wreg[5];
  {
    const i32x4* ws0 = (const i32x4*)wfrag;
    #pragma unroll
    for (int u2 = 0; u2 < 5; ++u2) wreg[u2] = ws0[tid + u2 * 256];
    #pragma unroll
    for (int u2 = 0; u2 < 5; ++u2) ((i32x4*)sw[0])[tid + u2 * 256] = wreg[u2];
  }

  for (int tg = 0; tg < 5; ++tg) {
    __syncthreads();
    if (tg < 4) {
      const i32x4* ws = (const i32x4*)(wfrag + (size_t)(tg + 1) * 10240);
      #pragma unroll
      for (int u2 = 0; u2 < 5; ++u2) wreg[u2] = ws[tid + u2 * 256];
    }
    const short* swb = sw[tg & 1];
    const int dy = tg - 2;
    #pragma unroll
    for (int tt = 0; tt < 5; ++tt) {
      const int tp = dy * RS + (tt - 2);
      int pin[4], sx4[4];
      #pragma unroll
      for (int i = 0; i < 4; ++i) {
        pin[i] = pinb[i] + tp;
        sx4[i] = swz2(pin[i]);
      }
      #pragma unroll
      for (int ks = 0; ks < 2; ++ks) {
        bf16x8 af[4];
        #pragma unroll
        for (int i = 0; i < 4; ++i)
          af[i] = *(const bf16x8*)&simg[pin[i] * 32 + (((ks * 2 + h) ^ sx4[i]) * 8)];
        #pragma unroll
        for (int nt = 0; nt < 2; ++nt) {
          const bf16x8 bf = *(const bf16x8*)&swb[(((tt * 2 + nt) * 2 + ks) * 64 + lane) * 8];
          #pragma unroll
          for (int i = 0; i < 4; ++i)
            acc[i][nt] = __builtin_amdgcn_mfma_f32_32x32x16_bf16(af[i], bf, acc[i][nt], 0, 0, 0);
        }
      }
    }
    if (tg < 4) {
      #pragma unroll
      for (int u2 = 0; u2 < 5; ++u2)
        ((i32x4*)sw[(tg + 1) & 1])[tid + u2 * 256] = wreg[u2];
    }
  }

  #pragma unroll
  for (int i = 0; i < 4; ++i) {
    #pragma unroll
    for (int nt = 0; nt < 2; ++nt) {
      const int oc = nt * 32 + l31;
      const float A = ab[oc], Bc = ab[64 + oc];
      #pragma unroll
      for (int g = 0; g < 4; ++g) {
        const int ppo = ppb[i] + 2 * g + h;
        if (uv2[i] && ppo < 98) {
          float mx = fmaxf(fmaxf(acc[i][nt][g * 4 + 0], acc[i][nt][g * 4 + 1]),
                           fmaxf(acc[i][nt][g * 4 + 2], acc[i][nt][g * 4 + 3]));
          float v = fminf(fmaxf(mx * A + Bc, -1.f), 1.f);
          out[((size_t)img * 196 + half * 98 + ppo) * 64 + oc] = f2bf(v);
        }
      }
    }
  }
}

// -------- conv3: 2 imgs, zero-halo 16x16 LDS, dbuf per-tap weights (R9) -----
__global__ __launch_bounds__(256, 2) void conv3_pad(
    const short* __restrict__ in, const short* __restrict__ wfrag,
    const float* __restrict__ ab, short* __restrict__ out) {
  constexpr int S = 8, RS = 16;
  __shared__ __align__(16) short simg[2 * 256 * 64];    // 65536 B
  __shared__ __align__(16) short sw[2][4096];           // 2 x 8 KB
  const int tid = threadIdx.x;
  const int img0 = blockIdx.x * 2;
  const int lane = tid & 63, wv = tid >> 6;
  const int l31 = lane & 31, h = lane >> 5;

  for (int c = tid; c < 960; c += 256) {
    int blk = c & 7, hp0 = c >> 3;
    int il = hp0 >= 60 ? 1 : 0, hp = hp0 - il * 60;
    int pin;
    if (hp < 32) pin = (hp >> 4) * 15 * RS + (hp & 15);
    else {
      int r = ((hp - 32) >> 1) + 1, cc = ((hp - 32) & 1) * 15;
      pin = r * RS + cc;
    }
    ((i32x4*)simg)[(il * 256 + pin) * S + blk] = (i32x4){0, 0, 0, 0};
  }
  {
    const i32x4* gin = (const i32x4*)(in + (size_t)img0 * 196 * 64);
    for (int c = tid; c < 3136; c += 256) {
      int il = c / 1568, r = c - il * 1568;
      int ps = r >> 3, blk = r & 7;
      int pin = (ps / 14 + 1) * RS + ps % 14 + 1;
      ((i32x4*)simg)[(il * 256 + pin) * S + (blk ^ swz3(pin))] = gin[c];
    }
  }

  int pinb[4], ppb[4], ilv[4];
  bool uv4[4];
  #pragma unroll
  for (int i = 0; i < 4; ++i) {
    int u = wv + i * 4;
    uv4[i] = u < 14;
    int uu = uv4[i] ? u : 0;
    int il = uu / 7, lt = uu - il * 7;
    int m = lt * 32 + l31, ppl = m >> 2, cd = m & 3;
    bool ok = uv4[i] && (ppl < 49);
    int py = ppl / 7, px = ppl - py * 7;
    int y = py * 2 + (cd >> 1), x = px * 2 + (cd & 1);
    pinb[i] = (ok ? ((y + 1) * RS + x + 1) : (RS + 1)) + il * 256;
    ilv[i] = il;
    ppb[i] = lt * 8;
  }

  f32x16 acc[4][2];
  #pragma unroll
  for (int i = 0; i < 4; ++i)
    #pragma unroll
    for (int nt = 0; nt < 2; ++nt)
      #pragma unroll
      for (int e = 0; e < 16; ++e) acc[i][nt][e] = 0.f;

  i32x4 wreg[2];
  {
    const i32x4* ws0 = (const i32x4*)wfrag;
    wreg[0] = ws0[tid];
    wreg[1] = ws0[tid + 256];
    ((i32x4*)sw[0])[tid] = wreg[0];
    ((i32x4*)sw[0])[tid + 256] = wreg[1];
  }

  for (int s = 0; s < 18; ++s) {
    __syncthreads();
    if (s < 17) {
      const i32x4* ws = (const i32x4*)(wfrag + (size_t)(s + 1) * 4096);
      wreg[0] = ws[tid];
      wreg[1] = ws[tid + 256];
    }
    const short* swb = sw[s & 1];
    const int t = s % 9;
    const int tp = (t / 3 - 1) * RS + (t % 3 - 1);
    int pin[4], sx4[4];
    #pragma unroll
    for (int i = 0; i < 4; ++i) {
      pin[i] = pinb[i] + tp;
      sx4[i] = swz3(pin[i]);
    }
    #pragma unroll
    for (int ks = 0; ks < 4; ++ks) {
      bf16x8 af[4];
      #pragma unroll
      for (int i = 0; i < 4; ++i)
        af[i] = *(const bf16x8*)&simg[pin[i] * 64 + (((ks * 2 + h) ^ sx4[i]) * 8)];
      #pragma unroll
      for (int nt = 0; nt < 2; ++nt) {
        const bf16x8 bf = *(const bf16x8*)&swb[((nt * 4 + ks) * 64 + lane) * 8];
        #pragma unroll
        for (int i = 0; i < 4; ++i)
          acc[i][nt] = __builtin_amdgcn_mfma_f32_32x32x16_bf16(af[i], bf, acc[i][nt], 0, 0, 0);
      }
    }
    if (s < 17) {
      ((i32x4*)sw[(s + 1) & 1])[tid] = wreg[0];
      ((i32x4*)sw[(s + 1) & 1])[tid + 256] = wreg[1];
    }
    if (t == 8) {
      const int ch = s / 9;
      #pragma unroll
      for (int i = 0; i < 4; ++i) {
        #pragma unroll
        for (int nt = 0; nt < 2; ++nt) {
          const int oc = ch * 64 + nt * 32 + l31;
          const float A = ab[oc], Bc = ab[128 + oc];
          #pragma unroll
          for (int g = 0; g < 4; ++g) {
            const int ppo = ppb[i] + 2 * g + h;
            if (uv4[i] && ppo < 49) {
              float mx = fmaxf(fmaxf(acc[i][nt][g * 4 + 0], acc[i][nt][g * 4 + 1]),
                               fmaxf(acc[i][nt][g * 4 + 2], acc[i][nt][g * 4 + 3]));
              float v = fminf(fmaxf(mx * A + Bc, -1.f), 1.f);
              out[((size_t)(img0 + ilv[i]) * 49 + ppo) * 128 + oc] = f2bf(v);
            }
          }
          #pragma unroll
          for (int e = 0; e < 16; ++e) acc[i][nt][e] = 0.f;
        }
      }
    }
  }
}

// -------- conv4: tap-outer dbuf weights (R9); emits h4 hi/lo fc-frag --------
__global__ __launch_bounds__(512, 2) void conv4_mfma(
    const short* __restrict__ in,      // h3 bf16 [img][49][128]
    const short* __restrict__ wfrag,   // [9][16][4][4][16][8]
    const float* __restrict__ ab,
    short* __restrict__ outH, short* __restrict__ outL) {
  constexpr int S = 16, NPIX = 49, PP = 9;
  __shared__ __align__(16) short simg[2 * NPIX * 128];
  __shared__ __align__(16) short swb[2][32768];
  const int tid = threadIdx.x;
  const int img0 = blockIdx.x * 2;
  const int lane = tid & 63, wv = tid >> 6;
  const int mrow = lane & 15, quad = lane >> 4;

  {
    const i32x4* gsrc = (const i32x4*)(in + (size_t)img0 * NPIX * 128);
    for (int c = tid; c < 2 * NPIX * S; c += 512) {
      int il = c / (NPIX * S);
      int r = c - il * (NPIX * S);
      int pix = r >> 4, blk = r & 15;
      ((i32x4*)simg)[il * NPIX * S + pix * S + (blk ^ (pix & 15))] = gsrc[c];
    }
    for (int u = tid; u < 4096; u += 512)
      ((i32x4*)swb[0])[u] = ((const i32x4*)wfrag)[u];
  }

  int yy[6], xx[6], ibs[6], ppo_[6], ilv[6];
  bool rv[6], pv[6];
  #pragma unroll
  for (int i = 0; i < 6; ++i) {
    int il = i / 3, lt = i - il * 3;
    int m = lt * 16 + mrow;
    int pp = m >> 2, cd = m & 3;
    rv[i] = pp < PP;
    int py = pp / 3, px = pp - py * 3;
    yy[i] = py * 2 + (cd >> 1);
    xx[i] = px * 2 + (cd & 1);
    ibs[i] = il * NPIX * S;
    ilv[i] = il;
    ppo_[i] = lt * 4 + quad;
    pv[i] = ppo_[i] < PP;
  }
  const int nt0 = wv, nt1 = wv + 8;
  f32x4 acc[6][2];
  #pragma unroll
  for (int i = 0; i < 6; ++i) {
    acc[i][0] = (f32x4){0.f, 0.f, 0.f, 0.f};
    acc[i][1] = (f32x4){0.f, 0.f, 0.f, 0.f};
  }
  __syncthreads();

  int dy = -1, dx = -1;
  for (int t = 0; t < 9; ++t) {
    const int buf = t & 1;
    if (t < 8) {
      const i32x4* wsrc = (const i32x4*)(wfrag + (size_t)(t + 1) * 32768);
      for (int u = tid; u < 4096; u += 512) ((i32x4*)swb[buf ^ 1])[u] = wsrc[u];
    }
    #pragma unroll
    for (int ks = 0; ks < 4; ++ks) {
      bf16x8 af[6];
      #pragma unroll
      for (int i = 0; i < 6; ++i) {
        int iy = yy[i] + dy, ix = xx[i] + dx;
        bool ok = rv[i] && (unsigned)iy < 7u && (unsigned)ix < 7u;
        int pin = iy * 7 + ix;
        int blk = (ks * 4 + quad) ^ (pin & 15);
        af[i] = ok ? *(const bf16x8*)&simg[(ibs[i] + pin * S + blk) * 8]
                   : (bf16x8){0, 0, 0, 0, 0, 0, 0, 0};
      }
      const bf16x8 b0 = *(const bf16x8*)&swb[buf][((nt0 * 4 + ks) * 4 + quad) * 128 + mrow * 8];
      const bf16x8 b1 = *(const bf16x8*)&swb[buf][((nt1 * 4 + ks) * 4 + quad) * 128 + mrow * 8];
      #pragma unroll
      for (int i = 0; i < 6; ++i) {
        acc[i][0] = __builtin_amdgcn_mfma_f32_16x16x32_bf16(af[i], b0, acc[i][0], 0, 0, 0);
        acc[i][1] = __builtin_amdgcn_mfma_f32_16x16x32_bf16(af[i], b1, acc[i][1], 0, 0, 0);
      }
    }
    dx++;
    if (dx == 2) { dx = -1; dy++; }
    __syncthreads();
  }

  #pragma unroll
  for (int i = 0; i < 6; ++i) {
    if (pv[i]) {
      #pragma unroll
      for (int nj = 0; nj < 2; ++nj) {
        const int oc = (nj ? nt1 : nt0) * 16 + mrow;
        const f32x4 a = acc[i][nj];
        float mx = fmaxf(fmaxf(a[0], a[1]), fmaxf(a[2], a[3]));
        float v = fminf(fmaxf(mx * ab[oc] + ab[256 + oc], -1.f), 1.f);
        const int m5 = (img0 + ilv[i]) * 9 + ppo_[i];
        size_t d = ((((((size_t)(m5 >> 6) * 2 + (oc >> 7)) * 4 + ((m5 >> 4) & 3)) * 4 +
                     ((oc >> 5) & 3)) * 4 + ((oc >> 3) & 3)) * 16 + (m5 & 15)) * 8 + (oc & 7);
        short hi = f2bf(v);
        outH[d] = hi;
        outL[d] = f2bf(v - bf2f(hi));
      }
    }
  }
}

// ------- fc MFMA GEMM (conv5 only): X/W from global, no LDS, no barriers ----
// OUTMODE 2: conv5 -> h5 frag (k1 = n*9 + m%9, m1 = m/9, KC2 chunks)
template <int KC, int OUTMODE, int KC2, int NALL>
__global__ __launch_bounds__(256, 4) void fc_mfma(
    const short* __restrict__ Xh, const short* __restrict__ Xl,
    const short* __restrict__ Wf, const float* __restrict__ ab,
    float* __restrict__ outF, short* __restrict__ outH, short* __restrict__ outL) {
  const int tid = threadIdx.x;
  const int bn = blockIdx.x, bm = blockIdx.y;
  const int lane = tid & 63, wv = tid >> 6;
  const int mrow = lane & 15, quad = lane >> 4;
  f32x4 acc[4];
  #pragma unroll
  for (int nt = 0; nt < 4; ++nt) acc[nt] = (f32x4){0.f, 0.f, 0.f, 0.f};

  for (int kc = 0; kc < KC; ++kc) {
    const short* xb = Xh + (((size_t)bm * KC + kc) * 4 + wv) * 2048;
    const short* xlb = Xl + (((size_t)bm * KC + kc) * 4 + wv) * 2048;
    const short* wb = Wf + ((size_t)bn * KC + kc) * 8192;
    #pragma unroll
    for (int ks = 0; ks < 4; ++ks) {
      const int ao = ((ks * 4 + quad) * 16 + mrow) * 8;
      const bf16x8 ah = *(const bf16x8*)&xb[ao];
      const bf16x8 al = *(const bf16x8*)&xlb[ao];
      #pragma unroll
      for (int nt = 0; nt < 4; ++nt) {
        const bf16x8 b = *(const bf16x8*)&wb[(((nt * 4 + ks) * 4 + quad) * 16 + mrow) * 8];
        acc[nt] = __builtin_amdgcn_mfma_f32_16x16x32_bf16(ah, b, acc[nt], 0, 0, 0);
        acc[nt] = __builtin_amdgcn_mfma_f32_16x16x32_bf16(al, b, acc[nt], 0, 0, 0);
      }
    }
  }

  #pragma unroll
  for (int nt = 0; nt < 4; ++nt) {
    const int n = bn * 64 + nt * 16 + mrow;
    const float A = ab[n], Bc = ab[NALL + n];
    #pragma unroll
    for (int r = 0; r < 4; ++r) {
      const int m = bm * 64 + wv * 16 + quad * 4 + r;
      float v = fminf(fmaxf(acc[nt][r] * A + Bc, -1.f), 1.f);
      if (OUTMODE == 0) {
        size_t d = (((((((size_t)(m >> 6) * KC2 + (n >> 7)) * 4 + ((m >> 4) & 3)) * 4 +
                       ((n >> 5) & 3)) * 4 + ((n >> 3) & 3)) * 16 + (m & 15))) * 8 + (n & 7);
        short hi = f2bf(v);
        outH[d] = hi;
        outL[d] = f2bf(v - bf2f(hi));
      } else if (OUTMODE == 1) {
        outF[(size_t)m * NALL + n] = v;
      } else {
        const int imgq = m / 9, p = m - imgq * 9;
        const int k1 = n * 9 + p;
        size_t d = ((((((size_t)(imgq >> 6) * KC2 + (k1 >> 7)) * 4 + ((imgq >> 4) & 3)) * 4 +
                     ((k1 >> 5) & 3)) * 4 + ((k1 >> 3) & 3)) * 16 + (imgq & 15)) * 8 + (k1 & 7);
        short hi = f2bf(v);
        outH[d] = hi;
        outL[d] = f2bf(v - bf2f(hi));
      }
    }
  }
}

// ------- fc K-split partial: raw fp32 partial sums, part = blockIdx.z -------
template <int KC, int KCP, int NALL>
__global__ __launch_bounds__(256, 4) void fc_mfma_part(
    const short* __restrict__ Xh, const short* __restrict__ Xl,
    const short* __restrict__ Wf, float* __restrict__ outP) {
  const int tid = threadIdx.x;
  const int bn = blockIdx.x, bm = blockIdx.y, pz = blockIdx.z;
  const int lane = tid & 63, wv = tid >> 6;
  const int mrow = lane & 15, quad = lane >> 4;
  f32x4 acc[4];
  #pragma unroll
  for (int nt = 0; nt < 4; ++nt) acc[nt] = (f32x4){0.f, 0.f, 0.f, 0.f};

  const int kc0 = pz * KCP;
  for (int kc = kc0; kc < kc0 + KCP; ++kc) {
    const short* xb = Xh + (((size_t)bm * KC + kc) * 4 + wv) * 2048;
    const short* xlb = Xl + (((size_t)bm * KC + kc) * 4 + wv) * 2048;
    const short* wb = Wf + ((size_t)bn * KC + kc) * 8192;
    #pragma unroll
    for (int ks = 0; ks < 4; ++ks) {
      const int ao = ((ks * 4 + quad) * 16 + mrow) * 8;
      const bf16x8 ah = *(const bf16x8*)&xb[ao];
      const bf16x8 al = *(const bf16x8*)&xlb[ao];
      #pragma unroll
      for (int nt = 0; nt < 4; ++nt) {
        const bf16x8 b = *(const bf16x8*)&wb[(((nt * 4 + ks) * 4 + quad) * 16 + mrow) * 8];
        acc[nt] = __builtin_amdgcn_mfma_f32_16x16x32_bf16(ah, b, acc[nt], 0, 0, 0);
        acc[nt] = __builtin_amdgcn_mfma_f32_16x16x32_bf16(al, b, acc[nt], 0, 0, 0);
      }
    }
  }

  const size_t M = (size_t)gridDim.y * 64;
  float* op = outP + (size_t)pz * M * NALL;
  #pragma unroll
  for (int nt = 0; nt < 4; ++nt) {
    const int n = bn * 64 + nt * 16 + mrow;
    #pragma unroll
    for (int r = 0; r < 4; ++r) {
      const int m = bm * 64 + wv * 16 + quad * 4 + r;
      op[(size_t)m * NALL + n] = acc[nt][r];
    }
  }
}

// ------- combine fc1 partials: sum 3, bn+ht, emit hi/lo frag (KC2=8) --------
__global__ __launch_bounds__(256) void combine_fc1(
    const float* __restrict__ part, const float* __restrict__ ab,
    short* __restrict__ outH, short* __restrict__ outL) {
  int i = blockIdx.x * 256 + threadIdx.x;      // 1048576
  int m = i >> 10, n = i & 1023;
  float v = part[i] + part[1048576 + i] + part[2097152 + i];
  v = fminf(fmaxf(v * ab[n] + ab[1024 + n], -1.f), 1.f);
  size_t d = (((((((size_t)(m >> 6) * 8 + (n >> 7)) * 4 + ((m >> 4) & 3)) * 4 +
                 ((n >> 5) & 3)) * 4 + ((n >> 3) & 3)) * 16 + (m & 15))) * 8 + (n & 7);
  short hi = f2bf(v);
  outH[d] = hi;
  outL[d] = f2bf(v - bf2f(hi));
}

// ------- combine fc2 partials: sum 4, bn+ht, fp32 row-major -----------------
__global__ __launch_bounds__(256) void combine_fc2(
    const float* __restrict__ part, const float* __restrict__ ab,
    float* __restrict__ out) {
  int i = blockIdx.x * 256 + threadIdx.x;      // 524288
  int n = i & 511;
  float v = part[i] + part[524288 + i] + part[1048576 + i] + part[1572864 + i];
  out[i] = fminf(fmaxf(v * ab[n] + ab[512 + n], -1.f), 1.f);
}

// ---------------- FC3 (float4 inner loop) ----------------
__global__ __launch_bounds__(256) void fc3_kernel(
    const float* __restrict__ X, const float* __restrict__ W,
    const float* __restrict__ bias, float* __restrict__ out) {
  __shared__ float ws[512 * 10 + 16];
  for (int li = threadIdx.x; li < 5120; li += 256) {
    int n = li / 512, k = li - n * 512;
    ws[k * 10 + n] = W[li];
  }
  __syncthreads();
  const int il = threadIdx.x >> 4, n = threadIdx.x & 15;
  const int img = blockIdx.x * 16 + il;
  if (n < 10) {
    const float4* xp = (const float4*)(X + (size_t)img * 512);
    float s = 0.f;
    for (int k4 = 0; k4 < 128; ++k4) {
      const float4 xv = xp[k4];
      const int k = k4 * 4;
      s += xv.x * ws[k * 10 + n];
      s += xv.y * ws[(k + 1) * 10 + n];
      s += xv.z * ws[(k + 2) * 10 + n];
      s += xv.w * ws[(k + 3) * 10 + n];
    }
    out[img * 10 + n] = s + bias[n];
  }
}

// ---------------- launch ----------------
extern "C" void kernel_launch(void* const* d_in, const int* in_sizes, int n_in,
                              void* d_out, int out_size, void* d_ws, size_t ws_size,
                              hipStream_t stream) {
  (void)in_sizes; (void)n_in; (void)out_size; (void)ws_size;
  const float* x = (const float*)d_in[0];
  float* W = (float*)d_ws;

  // workspace layout (floats)
  float* wsc  = W + 0;                       // 2304
  float* ab   = W + 2304;                    // 4608
  float* fq3  = W + 6912;                    // 5120
  short* wb1  = (short*)(W + 12032);         // 1024 sh
  short* wb2  = (short*)(W + 12544);         // 51200 sh
  short* wb3  = (short*)(W + 38144);         // 73728 sh
  short* wb4  = (short*)(W + 75008);         // 294912 sh
  short* wb5  = (short*)(W + 222464);        // 65536 sh
  short* fqb1 = (short*)(W + 255232);        // 2359296 sh
  short* fqb2 = (short*)(W + 1434880);       // 524288 sh
  short* h1   = (short*)(W + 1697024);       // [1024][784][32] bf16
  short* h2   = (short*)(W + 14542080);      // [1024][196][64] bf16
  short* h3   = (short*)(W + 20964608);      // [1024][49][128] bf16
  short* h4h  = (short*)(W + 24175872);      // fc-frag bf16 hi (M=9216,K=256)
  short* h4l  = (short*)(W + 25355520);      // fc-frag bf16 lo
  short* h5h  = (short*)(W + 26535168);      // fc-frag bf16 hi (M=1024,K=2304)
  short* h5l  = (short*)(W + 27714816);      // fc-frag bf16 lo
  short* f1h  = (short*)(W + 28894464);      // fc-frag bf16 hi (M=1024,N=1024)
  short* f1l  = (short*)(W + 29418752);      // fc-frag bf16 lo
  float* f2   = W + 29943040;                // [1024][512] = 524288
  float* fp1  = W + 30467328;                // fc1 partials [3][1024][1024]
  float* fp2  = W + 33613056;                // fc2 partials [4][1024][512]
  // ends at 35710208 floats (~143 MB)

  // 1) fused prep: scales + all repacks + fc3 dequant
  PrepArgs pa;
  const int widx[8] = {1, 7, 13, 19, 25, 31, 37, 43};
  short* pdst[8] = {wb1, wb2, wb3, wb4, wb5, fqb1, fqb2, nullptr};
  const int sco8[8] = {0, 32, 96, 224, 480, 736, 1760, 2272};
  const int cik8[8] = {25, 800, 576, 1152, 256, 2304, 1024, 512};
  const int co8[8] = {32, 64, 128, 256, 256, 1024, 512, 10};
  const int kind8[8] = {0, 1, 1, 2, 3, 3, 3, 4};
  const int KK8[8] = {25, 25, 9, 9, 1, 1, 1, 1};
  const int CI8[8] = {1, 32, 64, 128, 256, 2304, 1024, 512};
  const int OCCH8[8] = {32, 64, 64, 256, 256, 1024, 512, 10};
  const int KC8[8] = {1, 1, 1, 1, 2, 18, 8, 1};
  int cum = 0;
  for (int i = 0; i < 8; ++i) {
    pa.w[i] = (const float*)d_in[widx[i]];
    pa.dsth[i] = pdst[i];
    pa.sco[i] = sco8[i];
    pa.cik[i] = cik8[i];
    pa.kind[i] = kind8[i];
    pa.KK[i] = KK8[i];
    pa.CI[i] = CI8[i];
    pa.OCCH[i] = OCCH8[i];
    pa.KC[i] = KC8[i];
    pa.cum[i] = cum;
    cum += co8[i];
  }
  pa.cum[8] = cum;                  // 2282
  pa.dstf = fq3;
  pa.sc = wsc;
  hipLaunchKernelGGL(prep_all, dim3(cum), dim3(256), 0, stream, pa);

  // 2) fold BN (+ int-weight scale, all 7 layers)
  BnArgs ba;
  const int bbase[7] = {2, 8, 14, 20, 26, 32, 38};
  const int bc[7] = {32, 64, 128, 256, 256, 1024, 512};
  const int abo[7] = {0, 64, 192, 448, 960, 1472, 3520};
  int bcum = 0;
  for (int t = 0; t < 7; ++t) {
    for (int j = 0; j < 5; ++j) ba.p[t][j] = (const float*)d_in[bbase[t] + j];
    ba.C[t] = bc[t];
    ba.abo[t] = abo[t];
    ba.sco[t] = sco8[t];
    ba.cum[t] = bcum;
    bcum += bc[t];
  }
  ba.cum[7] = bcum;
  ba.ab = ab;
  ba.wsc = wsc;
  hipLaunchKernelGGL(bn_all, dim3((bcum + 255) / 256), dim3(256), 0, stream, ba);

  // 3) conv stack
  hipLaunchKernelGGL(conv1_mfma, dim3(1024), dim3(448), 0, stream,
                     x, wb1, ab + 0, h1);
  hipLaunchKernelGGL(conv2_half, dim3(2048), dim3(256), 0, stream,
                     h1, wb2, ab + 64, h2);
  hipLaunchKernelGGL(conv3_pad, dim3(512), dim3(256), 0, stream,
                     h2, wb3, ab + 192, h3);
  hipLaunchKernelGGL(conv4_mfma, dim3(512), dim3(512), 0, stream,
                     h3, wb4, ab + 448, h4h, h4l);
  hipLaunchKernelGGL((fc_mfma<2, 2, 18, 256>), dim3(4, 144), dim3(256), 0, stream,
                     h4h, h4l, wb5, ab + 960, nullptr, h5h, h5l);

  // 4) FC stack (K-split + combine)
  hipLaunchKernelGGL((fc_mfma_part<18, 6, 1024>), dim3(16, 16, 3), dim3(256), 0, stream,
                     h5h, h5l, fqb1, fp1);
  hipLaunchKernelGGL(combine_fc1, dim3(4096), dim3(256), 0, stream,
                     fp1, ab + 1472, f1h, f1l);
  hipLaunchKernelGGL((fc_mfma_part<8, 2, 512>), dim3(8, 16, 4), dim3(256), 0, stream,
                     f1h, f1l, fqb2, fp2);
  hipLaunchKernelGGL(combine_fc2, dim3(2048), dim3(256), 0, stream,
                     fp2, ab + 3520, f2);
  hipLaunchKernelGGL(fc3_kernel, dim3(64), dim3(256), 0, stream,
                     f2, fq3, (const float*)d_in[44], (float*)d_out);
}